// Round 3
// baseline (9099.377 us; speedup 1.0000x reference)
//
#include <hip/hip_runtime.h>
#include <hip/hip_bf16.h>
#include <math.h>

// Problem constants: B=2, S=2048, E=1024, H=16, D=64, buckets used: 0..127 (causal => rel>=0)

static __device__ __forceinline__ unsigned short f2bf(float x) {
    unsigned u = __float_as_uint(x);
    unsigned r = (u + 0x7fffu + ((u >> 16) & 1u)) >> 16;   // RNE
    return (unsigned short)r;
}
static __device__ __forceinline__ float bf2f(unsigned short h) {
    return __uint_as_float(((unsigned)h) << 16);
}

// ---------------- SGEMM 128x128 tile, K-step 16, fp32 ----------------
// MODE 0: C[m*1024+n] plain row-major   MODE 1: scatter to [B,H,S,D] head layout
template<int MODE>
__global__ void sgemm128(const float* __restrict__ A, const float* __restrict__ W,
                         float* __restrict__ C)
{
    __shared__ float As[16*128];   // As[k][m]
    __shared__ float Bs[16*128];   // Bs[k][n]
    const int tid = threadIdx.x;
    const int tx = tid & 15, ty = tid >> 4;
    const int bx = blockIdx.x, by = blockIdx.y;
    const int arow = tid >> 1;          // 0..127
    const int acol = (tid & 1) * 8;     // 0 or 8
    const int brow = tid >> 4;          // 0..15
    const int bcol = (tid & 15) * 8;    // 0..120

    float acc[8][8];
#pragma unroll
    for (int i = 0; i < 8; ++i)
#pragma unroll
        for (int j = 0; j < 8; ++j) acc[i][j] = 0.f;

    const float* ap = A + (size_t)(by*128 + arow)*1024 + acol;
    const float* bp = W + (size_t)brow*1024 + bx*128 + bcol;

    for (int k0 = 0; k0 < 1024; k0 += 16) {
        float4 a0 = *(const float4*)(ap + k0);
        float4 a1 = *(const float4*)(ap + k0 + 4);
        float4 b0 = *(const float4*)(bp + (size_t)k0*1024);
        float4 b1 = *(const float4*)(bp + (size_t)k0*1024 + 4);
        As[(acol+0)*128 + arow] = a0.x;
        As[(acol+1)*128 + arow] = a0.y;
        As[(acol+2)*128 + arow] = a0.z;
        As[(acol+3)*128 + arow] = a0.w;
        As[(acol+4)*128 + arow] = a1.x;
        As[(acol+5)*128 + arow] = a1.y;
        As[(acol+6)*128 + arow] = a1.z;
        As[(acol+7)*128 + arow] = a1.w;
        *(float4*)&Bs[brow*128 + bcol]     = b0;
        *(float4*)&Bs[brow*128 + bcol + 4] = b1;
        __syncthreads();
#pragma unroll
        for (int kk = 0; kk < 16; ++kk) {
            float a[8], b[8];
            *(float4*)&a[0] = *(const float4*)&As[kk*128 + ty*8];
            *(float4*)&a[4] = *(const float4*)&As[kk*128 + ty*8 + 4];
            *(float4*)&b[0] = *(const float4*)&Bs[kk*128 + tx*8];
            *(float4*)&b[4] = *(const float4*)&Bs[kk*128 + tx*8 + 4];
#pragma unroll
            for (int i = 0; i < 8; ++i)
#pragma unroll
                for (int j = 0; j < 8; ++j)
                    acc[i][j] = fmaf(a[i], b[j], acc[i][j]);
        }
        __syncthreads();
    }
    const int n0 = bx*128 + tx*8;
#pragma unroll
    for (int i = 0; i < 8; ++i) {
        const int m = by*128 + ty*8 + i;
        float4 st0 = make_float4(acc[i][0], acc[i][1], acc[i][2], acc[i][3]);
        float4 st1 = make_float4(acc[i][4], acc[i][5], acc[i][6], acc[i][7]);
        if (MODE == 0) {
            float* o = C + (size_t)m*1024 + n0;
            *(float4*)o     = st0;
            *(float4*)(o+4) = st1;
        } else {
            const int bb = m >> 11, ss = m & 2047;
            const int hh = n0 >> 6, dd = n0 & 63;   // 8-col chunk never crosses a head
            float* o = C + ((((size_t)bb*16 + hh)*2048 + ss)*64 + dd);
            *(float4*)o     = st0;
            *(float4*)(o+4) = st1;
        }
    }
}

// ---------------- RoPE (in place on q and k, [B,H,S,D]) ----------------
__global__ void rope_kernel(float* __restrict__ q, float* __restrict__ k)
{
    const int t = blockIdx.x * 256 + threadIdx.x;    // 0 .. 2^22-1
    const int ten = t >> 21;                         // 0:q 1:k
    const int r = t & ((1 << 21) - 1);
    const int dd = r & 31;                           // low half element
    const int s  = (r >> 5) & 2047;
    const int bh = r >> 16;                          // 0..31
    float* p = ten ? k : q;
    const size_t base = ((size_t)bh*2048 + s)*64;
    const float x0 = p[base + dd];
    const float x1 = p[base + dd + 32];
    const float f0 = (float)(dd >> 1);
    const float CC = 0.41524101186092029f;           // log2(10000)/32
    const float if0 = exp2f(-f0 * CC);
    const float if1 = exp2f(-(f0 + 16.f) * CC);
    const float a0 = (float)s * if0;
    const float a1 = (float)s * if1;
    p[base + dd]      = x0 * cosf(a0) - x1 * sinf(a0);
    p[base + dd + 32] = x1 * cosf(a1) + x0 * sinf(a1);
}

// ---------------- q_rel = q . rel_emb  ->  [B*H, S, 128] ----------------
__global__ void qrel_kernel(const float* __restrict__ q, const float* __restrict__ rel_emb,
                            float* __restrict__ qrel)
{
    __shared__ float qs[64*65];
    __shared__ float rls[128*64];
    const int tid = threadIdx.x;
    const int s0 = blockIdx.x * 64;
    const int bh = blockIdx.y;
    const int h  = bh & 15;

    for (int idx = tid; idx < 64*16; idx += 256) {
        int r = idx >> 4, c4 = (idx & 15) << 2;
        float4 vv = *(const float4*)(q + ((size_t)bh*2048 + s0 + r)*64 + c4);
        qs[r*65 + c4 + 0] = vv.x;
        qs[r*65 + c4 + 1] = vv.y;
        qs[r*65 + c4 + 2] = vv.z;
        qs[r*65 + c4 + 3] = vv.w;
    }
    for (int idx = tid; idx < 128*16; idx += 256) {
        int n = idx >> 4, c4 = (idx & 15) << 2;
        *(float4*)&rls[n*64 + c4] = *(const float4*)(rel_emb + ((size_t)n*16 + h)*64 + c4);
    }
    __syncthreads();

    const int r  = tid & 63;
    const int nb = tid >> 6;
    float* orow = qrel + ((size_t)bh*2048 + s0 + r)*128;
#pragma unroll 1
    for (int kq = 0; kq < 8; ++kq) {
        const int n0 = nb*4 + kq*16;
        float a0 = 0.f, a1 = 0.f, a2 = 0.f, a3 = 0.f;
#pragma unroll
        for (int d = 0; d < 64; ++d) {
            const float qv = qs[r*65 + d];
            a0 = fmaf(qv, rls[(n0+0)*64 + d], a0);
            a1 = fmaf(qv, rls[(n0+1)*64 + d], a1);
            a2 = fmaf(qv, rls[(n0+2)*64 + d], a2);
            a3 = fmaf(qv, rls[(n0+3)*64 + d], a3);
        }
        float4 st = make_float4(a0, a1, a2, a3);
        *(float4*)&orow[n0] = st;
    }
}

// ---------------- causal flash attention, 256 thr / 4 waves / 64 q-rows ----------------
// 4 lanes per q-row (16 dims each). K/V 32-row tiles (fp32) + bf16 bias rows in LDS.
// LDS = 2*32*68*4 + 64*132*2 = 34304 B -> 4 blocks/CU; launch_bounds(256,3) -> VGPR<=168.
__global__ __launch_bounds__(256, 3) void flash_kernel(
    const float* __restrict__ q, const float* __restrict__ k,
    const float* __restrict__ v, const float* __restrict__ qrel,
    float* __restrict__ ctx)
{
    __shared__ float kls[32][68];
    __shared__ float vls[32][68];
    __shared__ unsigned short qrels[64*132];   // bf16 bias rows, pad 132
    const int tid = threadIdx.x;
    const int i0 = blockIdx.x * 64;
    const int bh = blockIdx.y;
    const int wave = tid >> 6;
    const int lane = tid & 63;
    const int row  = wave*16 + (lane >> 2);   // local q-row 0..63
    const int c    = lane & 3;                // dim chunk: c*16 .. c*16+15
    const int i    = i0 + row;

    // stage bias rows (fp32 global -> bf16 LDS)
    for (int idx = tid; idx < 64*32; idx += 256) {
        const int r  = idx >> 5;
        const int c4 = (idx & 31) << 2;
        float4 vv = *(const float4*)(qrel + ((size_t)bh*2048 + i0 + r)*128 + c4);
        unsigned short* dst = &qrels[r*132 + c4];
        dst[0] = f2bf(vv.x); dst[1] = f2bf(vv.y);
        dst[2] = f2bf(vv.z); dst[3] = f2bf(vv.w);
    }

    // q fragment: 16 dims
    float qreg[16];
    {
        const float* qrow = q + ((size_t)bh*2048 + i)*64 + c*16;
#pragma unroll
        for (int cc = 0; cc < 4; ++cc) {
            float4 vv = ((const float4*)qrow)[cc];
            qreg[4*cc+0] = vv.x; qreg[4*cc+1] = vv.y;
            qreg[4*cc+2] = vv.z; qreg[4*cc+3] = vv.w;
        }
    }
    float acc[16];
#pragma unroll
    for (int d = 0; d < 16; ++d) acc[d] = 0.f;
    float mrun = -INFINITY, lsum = 0.f;

    // staging roles: tids 0..127 -> K, 128..255 -> V ; each thread 16 consecutive floats
    const int srow = (tid & 127) >> 2;
    const int scol = (tid & 3) * 16;
    const float* ssrc = ((tid < 128) ? k : v) + ((size_t)bh*2048 + srow)*64 + scol;
    float* sdst = (tid < 128) ? &kls[srow][scol] : &vls[srow][scol];

    const int ntiles = (i0 >> 5) + 2;
    const float SCL = 0.1803368801111204f;   // (1/8) * log2(e); exp2-based softmax

    // prefetch tile 0
    float4 ld0, ld1, ld2, ld3;
    {
        const float4* src4 = (const float4*)ssrc;
        ld0 = src4[0]; ld1 = src4[1]; ld2 = src4[2]; ld3 = src4[3];
    }

    for (int t = 0; t < ntiles; ++t) {
        const int j0 = t * 32;
        __syncthreads();   // prev tile consumed (t=0: qrels staged)
        {
            float4* dst4 = (float4*)sdst;
            dst4[0] = ld0; dst4[1] = ld1; dst4[2] = ld2; dst4[3] = ld3;
        }
        __syncthreads();
        if (t + 1 < ntiles) {   // prefetch next tile during compute
            const float4* src4 = (const float4*)(ssrc + (size_t)(j0 + 32)*64);
            ld0 = src4[0]; ld1 = src4[1]; ld2 = src4[2]; ld3 = src4[3];
        }

        // partial dots over this lane's 16 dims
        float sv[32];
#pragma unroll
        for (int kk = 0; kk < 32; ++kk) {
            const float4* kr = (const float4*)&kls[kk][c*16];
            float dot = 0.f;
#pragma unroll
            for (int cc = 0; cc < 4; ++cc) {
                float4 kv = kr[cc];
                dot = fmaf(qreg[4*cc+0], kv.x, dot);
                dot = fmaf(qreg[4*cc+1], kv.y, dot);
                dot = fmaf(qreg[4*cc+2], kv.z, dot);
                dot = fmaf(qreg[4*cc+3], kv.w, dot);
            }
            sv[kk] = dot;
        }
        // reduce across 4-lane group; add bias, scale (base-2), mask
        float tmax = -INFINITY;
#pragma unroll
        for (int kk = 0; kk < 32; ++kk) {
            float dot = sv[kk];
            dot += __shfl_xor(dot, 1);
            dot += __shfl_xor(dot, 2);
            const int rel = i - (j0 + kk);
            int bkt;
            if (rel < 64) {
                bkt = (rel < 0) ? 0 : rel;
            } else {
                bkt = 64 + (int)(log2f((float)rel * 0.015625f) * 8.0f);
                bkt = bkt > 127 ? 127 : bkt;
            }
            const float bias = bf2f(qrels[row*132 + bkt]);
            const float sfull = (dot + bias) * SCL;
            sv[kk] = (rel >= 0) ? sfull : -1e30f;
            tmax = fmaxf(tmax, sv[kk]);
        }
        const float newm = fmaxf(mrun, tmax);
        const float corr = exp2f(mrun - newm);   // exp2(-inf)=0 on first tile
        lsum *= corr;
#pragma unroll
        for (int d = 0; d < 16; ++d) acc[d] *= corr;
#pragma unroll
        for (int kk = 0; kk < 32; ++kk) {
            const float p = exp2f(sv[kk] - newm);
            lsum += p;
            const float4* vr = (const float4*)&vls[kk][c*16];
#pragma unroll
            for (int cc = 0; cc < 4; ++cc) {
                float4 vv = vr[cc];
                acc[4*cc+0] = fmaf(p, vv.x, acc[4*cc+0]);
                acc[4*cc+1] = fmaf(p, vv.y, acc[4*cc+1]);
                acc[4*cc+2] = fmaf(p, vv.z, acc[4*cc+2]);
                acc[4*cc+3] = fmaf(p, vv.w, acc[4*cc+3]);
            }
        }
        mrun = newm;
    }

    const float inv = 1.0f / lsum;
    // ctx layout [B,S,H,D]
    float* orow = ctx + ((((size_t)(bh >> 4))*2048 + i)*16 + (bh & 15))*64 + c*16;
#pragma unroll
    for (int cc = 0; cc < 4; ++cc) {
        float4 st = make_float4(acc[4*cc+0]*inv, acc[4*cc+1]*inv,
                                acc[4*cc+2]*inv, acc[4*cc+3]*inv);
        ((float4*)orow)[cc] = st;
    }
}

extern "C" void kernel_launch(void* const* d_in, const int* in_sizes, int n_in,
                              void* d_out, int out_size, void* d_ws, size_t ws_size,
                              hipStream_t stream)
{
    const float* x   = (const float*)d_in[0];
    const float* Wq  = (const float*)d_in[1];
    const float* Wk  = (const float*)d_in[2];
    const float* Wv  = (const float*)d_in[3];
    const float* Wo  = (const float*)d_in[4];
    const float* rel = (const float*)d_in[5];

    float* ws   = (float*)d_ws;
    float* q    = ws;                    // [B,H,S,D]
    float* kbuf = ws + 4194304;          // [B,H,S,D]
    float* vbuf = ws + 8388608;          // [B,H,S,D]
    float* qrel = ws + 12582912;         // [B*H,S,128]
    float* ctx  = ws + 20971520;         // [B,S,H,D]

    dim3 gemm_grid(8, 32);
    sgemm128<1><<<gemm_grid, 256, 0, stream>>>(x, Wq, q);
    sgemm128<1><<<gemm_grid, 256, 0, stream>>>(x, Wk, kbuf);
    sgemm128<1><<<gemm_grid, 256, 0, stream>>>(x, Wv, vbuf);
    rope_kernel<<<16384, 256, 0, stream>>>(q, kbuf);
    qrel_kernel<<<dim3(32, 32), 256, 0, stream>>>(q, rel, qrel);
    flash_kernel<<<dim3(32, 32), 256, 0, stream>>>(q, kbuf, vbuf, qrel, ctx);
    sgemm128<0><<<gemm_grid, 256, 0, stream>>>(ctx, Wo, (float*)d_out);
}

// Round 4
// 4611.285 us; speedup vs baseline: 1.9733x; 1.9733x over previous
//
#include <hip/hip_runtime.h>
#include <hip/hip_bf16.h>
#include <math.h>

// Problem constants: B=2, S=2048, E=1024, H=16, D=64, buckets used: 0..127 (causal => rel>=0)

static __device__ __forceinline__ unsigned short f2bf(float x) {
    unsigned u = __float_as_uint(x);
    unsigned r = (u + 0x7fffu + ((u >> 16) & 1u)) >> 16;   // RNE
    return (unsigned short)r;
}
static __device__ __forceinline__ float bf2f(unsigned short h) {
    return __uint_as_float(((unsigned)h) << 16);
}

// async 16B global->LDS (wave-uniform LDS base + lane*16, so LDS layout must be linear)
#define GLOAD16(gp, lp)                                                            \
    __builtin_amdgcn_global_load_lds(                                              \
        (const __attribute__((address_space(1))) unsigned int*)(gp),               \
        (__attribute__((address_space(3))) unsigned int*)(lp), 16, 0, 0)

// ---------------- SGEMM 128x128 tile, K-step 16, fp32 ----------------
// MODE 0: C[m*1024+n] plain row-major   MODE 1: scatter to [B,H,S,D] head layout
template<int MODE>
__global__ void sgemm128(const float* __restrict__ A, const float* __restrict__ W,
                         float* __restrict__ C)
{
    __shared__ float As[16*128];   // As[k][m]
    __shared__ float Bs[16*128];   // Bs[k][n]
    const int tid = threadIdx.x;
    const int tx = tid & 15, ty = tid >> 4;
    const int bx = blockIdx.x, by = blockIdx.y;
    const int arow = tid >> 1;          // 0..127
    const int acol = (tid & 1) * 8;     // 0 or 8
    const int brow = tid >> 4;          // 0..15
    const int bcol = (tid & 15) * 8;    // 0..120

    float acc[8][8];
#pragma unroll
    for (int i = 0; i < 8; ++i)
#pragma unroll
        for (int j = 0; j < 8; ++j) acc[i][j] = 0.f;

    const float* ap = A + (size_t)(by*128 + arow)*1024 + acol;
    const float* bp = W + (size_t)brow*1024 + bx*128 + bcol;

    for (int k0 = 0; k0 < 1024; k0 += 16) {
        float4 a0 = *(const float4*)(ap + k0);
        float4 a1 = *(const float4*)(ap + k0 + 4);
        float4 b0 = *(const float4*)(bp + (size_t)k0*1024);
        float4 b1 = *(const float4*)(bp + (size_t)k0*1024 + 4);
        As[(acol+0)*128 + arow] = a0.x;
        As[(acol+1)*128 + arow] = a0.y;
        As[(acol+2)*128 + arow] = a0.z;
        As[(acol+3)*128 + arow] = a0.w;
        As[(acol+4)*128 + arow] = a1.x;
        As[(acol+5)*128 + arow] = a1.y;
        As[(acol+6)*128 + arow] = a1.z;
        As[(acol+7)*128 + arow] = a1.w;
        *(float4*)&Bs[brow*128 + bcol]     = b0;
        *(float4*)&Bs[brow*128 + bcol + 4] = b1;
        __syncthreads();
#pragma unroll
        for (int kk = 0; kk < 16; ++kk) {
            float a[8], b[8];
            *(float4*)&a[0] = *(const float4*)&As[kk*128 + ty*8];
            *(float4*)&a[4] = *(const float4*)&As[kk*128 + ty*8 + 4];
            *(float4*)&b[0] = *(const float4*)&Bs[kk*128 + tx*8];
            *(float4*)&b[4] = *(const float4*)&Bs[kk*128 + tx*8 + 4];
#pragma unroll
            for (int i = 0; i < 8; ++i)
#pragma unroll
                for (int j = 0; j < 8; ++j)
                    acc[i][j] = fmaf(a[i], b[j], acc[i][j]);
        }
        __syncthreads();
    }
    const int n0 = bx*128 + tx*8;
#pragma unroll
    for (int i = 0; i < 8; ++i) {
        const int m = by*128 + ty*8 + i;
        float4 st0 = make_float4(acc[i][0], acc[i][1], acc[i][2], acc[i][3]);
        float4 st1 = make_float4(acc[i][4], acc[i][5], acc[i][6], acc[i][7]);
        if (MODE == 0) {
            float* o = C + (size_t)m*1024 + n0;
            *(float4*)o     = st0;
            *(float4*)(o+4) = st1;
        } else {
            const int bb = m >> 11, ss = m & 2047;
            const int hh = n0 >> 6, dd = n0 & 63;   // 8-col chunk never crosses a head
            float* o = C + ((((size_t)bb*16 + hh)*2048 + ss)*64 + dd);
            *(float4*)o     = st0;
            *(float4*)(o+4) = st1;
        }
    }
}

// ---------------- RoPE (in place on q and k, [B,H,S,D]) ----------------
__global__ void rope_kernel(float* __restrict__ q, float* __restrict__ k)
{
    const int t = blockIdx.x * 256 + threadIdx.x;    // 0 .. 2^22-1
    const int ten = t >> 21;                         // 0:q 1:k
    const int r = t & ((1 << 21) - 1);
    const int dd = r & 31;                           // low half element
    const int s  = (r >> 5) & 2047;
    const int bh = r >> 16;                          // 0..31
    float* p = ten ? k : q;
    const size_t base = ((size_t)bh*2048 + s)*64;
    const float x0 = p[base + dd];
    const float x1 = p[base + dd + 32];
    const float f0 = (float)(dd >> 1);
    const float CC = 0.41524101186092029f;           // log2(10000)/32
    const float if0 = exp2f(-f0 * CC);
    const float if1 = exp2f(-(f0 + 16.f) * CC);
    const float a0 = (float)s * if0;
    const float a1 = (float)s * if1;
    p[base + dd]      = x0 * cosf(a0) - x1 * sinf(a0);
    p[base + dd + 32] = x1 * cosf(a1) + x0 * sinf(a1);
}

// ---------------- q_rel = q . rel_emb  ->  [B*H, S, 128] ----------------
__global__ void qrel_kernel(const float* __restrict__ q, const float* __restrict__ rel_emb,
                            float* __restrict__ qrel)
{
    __shared__ float qs[64*65];
    __shared__ float rls[128*64];
    const int tid = threadIdx.x;
    const int s0 = blockIdx.x * 64;
    const int bh = blockIdx.y;
    const int h  = bh & 15;

    for (int idx = tid; idx < 64*16; idx += 256) {
        int r = idx >> 4, c4 = (idx & 15) << 2;
        float4 vv = *(const float4*)(q + ((size_t)bh*2048 + s0 + r)*64 + c4);
        qs[r*65 + c4 + 0] = vv.x;
        qs[r*65 + c4 + 1] = vv.y;
        qs[r*65 + c4 + 2] = vv.z;
        qs[r*65 + c4 + 3] = vv.w;
    }
    for (int idx = tid; idx < 128*16; idx += 256) {
        int n = idx >> 4, c4 = (idx & 15) << 2;
        *(float4*)&rls[n*64 + c4] = *(const float4*)(rel_emb + ((size_t)n*16 + h)*64 + c4);
    }
    __syncthreads();

    const int r  = tid & 63;
    const int nb = tid >> 6;
    float* orow = qrel + ((size_t)bh*2048 + s0 + r)*128;
#pragma unroll 1
    for (int kq = 0; kq < 8; ++kq) {
        const int n0 = nb*4 + kq*16;
        float a0 = 0.f, a1 = 0.f, a2 = 0.f, a3 = 0.f;
#pragma unroll
        for (int d = 0; d < 64; ++d) {
            const float qv = qs[r*65 + d];
            a0 = fmaf(qv, rls[(n0+0)*64 + d], a0);
            a1 = fmaf(qv, rls[(n0+1)*64 + d], a1);
            a2 = fmaf(qv, rls[(n0+2)*64 + d], a2);
            a3 = fmaf(qv, rls[(n0+3)*64 + d], a3);
        }
        float4 st = make_float4(a0, a1, a2, a3);
        *(float4*)&orow[n0] = st;
    }
}

// ---------------- causal flash attention, 256 thr / 4 waves / 64 q-rows ----------------
// 4 lanes per q-row (16 dims each). K/V 32x64 tiles staged via global_load_lds (linear),
// bf16 bias rows in LDS. LDS = 2*8192 + 64*132*2 = 33280 B; VGPR<=128 -> 4 blocks/CU,
// all 1024 blocks resident. Balanced bx map + per-XCD head locality.
__global__ __launch_bounds__(256, 2) void flash_kernel(
    const float* __restrict__ q, const float* __restrict__ k,
    const float* __restrict__ v, const float* __restrict__ qrel,
    float* __restrict__ ctx)
{
    __shared__ float kls[32*64];
    __shared__ float vls[32*64];
    __shared__ unsigned short qrels[64*132];   // bf16 bias rows, pad 132

    const int tid = threadIdx.x;
    const int id  = blockIdx.x;
    const int bh  = id & 31;                   // all blocks of a head -> same XCD (id%8 fixed)
    const int m   = id >> 5;
    const int a   = m & 7, b = m >> 3;
    const int bx  = 8*b + ((b & 1) ? 7 - a : a);   // bijection; per-CU tile-work ~constant
    const int i0  = bx * 64;

    const int wave = tid >> 6;
    const int lane = tid & 63;
    const int row  = wave*16 + (lane >> 2);    // local q-row 0..63
    const int c    = lane & 3;                 // dim chunk: c*16 .. c*16+15
    const int i    = i0 + row;

    // stage bias rows (fp32 global -> bf16 LDS)
    for (int idx = tid; idx < 64*32; idx += 256) {
        const int r  = idx >> 5;
        const int c4 = (idx & 31) << 2;
        float4 vv = *(const float4*)(qrel + ((size_t)bh*2048 + i0 + r)*128 + c4);
        unsigned short* dst = &qrels[r*132 + c4];
        dst[0] = f2bf(vv.x); dst[1] = f2bf(vv.y);
        dst[2] = f2bf(vv.z); dst[3] = f2bf(vv.w);
    }

    // q fragment: 16 dims
    float qreg[16];
    {
        const float* qrow = q + ((size_t)bh*2048 + i)*64 + c*16;
#pragma unroll
        for (int cc = 0; cc < 4; ++cc) {
            float4 vv = ((const float4*)qrow)[cc];
            qreg[4*cc+0] = vv.x; qreg[4*cc+1] = vv.y;
            qreg[4*cc+2] = vv.z; qreg[4*cc+3] = vv.w;
        }
    }
    float acc[16];
#pragma unroll
    for (int d = 0; d < 16; ++d) acc[d] = 0.f;
    float mrun = -INFINITY, lsum = 0.f;

    // staging: wave 0,1 -> K rows 0-15/16-31 ; wave 2,3 -> V. One 8KB tile = 8 wave-loads.
    const char* gbase = (const char*)(((wave < 2) ? k : v) + (size_t)bh*2048*64)
                        + ((wave & 1) * 4096 + lane * 16);
    char* lbase = (char*)((wave < 2) ? kls : vls) + ((wave & 1) * 4096 + lane * 16);

    const int ntiles = (i0 >> 5) + 2;
    const float SCL = 0.1803368801111204f;   // (1/8) * log2(e); exp2-based softmax

    for (int t = 0; t < ntiles; ++t) {
        const int j0 = t * 32;
        __syncthreads();                      // prev tile consumed (t=0: qrels staged)
        {
            const char* g = gbase + (size_t)j0 * 256;
            GLOAD16(g + 0,    lbase + 0);
            GLOAD16(g + 1024, lbase + 1024);
            GLOAD16(g + 2048, lbase + 2048);
            GLOAD16(g + 3072, lbase + 3072);
        }
        __syncthreads();                      // vmcnt drained -> tile visible

        // partial dots over this lane's 16 dims
        float sv[32];
#pragma unroll
        for (int kk = 0; kk < 32; ++kk) {
            const float4* kr = (const float4*)&kls[kk*64 + c*16];
            float dot = 0.f;
#pragma unroll
            for (int cc = 0; cc < 4; ++cc) {
                float4 kv = kr[cc];
                dot = fmaf(qreg[4*cc+0], kv.x, dot);
                dot = fmaf(qreg[4*cc+1], kv.y, dot);
                dot = fmaf(qreg[4*cc+2], kv.z, dot);
                dot = fmaf(qreg[4*cc+3], kv.w, dot);
            }
            sv[kk] = dot;
        }
        // reduce across 4-lane group; add bias, scale (base-2), mask
        float tmax = -INFINITY;
#pragma unroll
        for (int kk = 0; kk < 32; ++kk) {
            float dot = sv[kk];
            dot += __shfl_xor(dot, 1);
            dot += __shfl_xor(dot, 2);
            const int rel = i - (j0 + kk);
            int bkt;
            if (rel < 64) {
                bkt = (rel < 0) ? 0 : rel;
            } else {
                bkt = 64 + (int)(__log2f((float)rel) * 8.0f - 48.0f);
                bkt = bkt > 127 ? 127 : bkt;
            }
            const float bias = bf2f(qrels[row*132 + bkt]);
            const float sfull = (dot + bias) * SCL;
            sv[kk] = (rel >= 0) ? sfull : -1e30f;
            tmax = fmaxf(tmax, sv[kk]);
        }
        const float newm = fmaxf(mrun, tmax);
        const float corr = exp2f(mrun - newm);   // exp2(-inf)=0 on first tile
        lsum *= corr;
#pragma unroll
        for (int d = 0; d < 16; ++d) acc[d] *= corr;
#pragma unroll
        for (int kk = 0; kk < 32; ++kk) {
            const float p = exp2f(sv[kk] - newm);
            lsum += p;
            const float4* vr = (const float4*)&vls[kk*64 + c*16];
#pragma unroll
            for (int cc = 0; cc < 4; ++cc) {
                float4 vv = vr[cc];
                acc[4*cc+0] = fmaf(p, vv.x, acc[4*cc+0]);
                acc[4*cc+1] = fmaf(p, vv.y, acc[4*cc+1]);
                acc[4*cc+2] = fmaf(p, vv.z, acc[4*cc+2]);
                acc[4*cc+3] = fmaf(p, vv.w, acc[4*cc+3]);
            }
        }
        mrun = newm;
    }

    const float inv = 1.0f / lsum;
    // ctx layout [B,S,H,D]
    float* orow = ctx + ((((size_t)(bh >> 4))*2048 + i)*16 + (bh & 15))*64 + c*16;
#pragma unroll
    for (int cc = 0; cc < 4; ++cc) {
        float4 st = make_float4(acc[4*cc+0]*inv, acc[4*cc+1]*inv,
                                acc[4*cc+2]*inv, acc[4*cc+3]*inv);
        ((float4*)orow)[cc] = st;
    }
}

extern "C" void kernel_launch(void* const* d_in, const int* in_sizes, int n_in,
                              void* d_out, int out_size, void* d_ws, size_t ws_size,
                              hipStream_t stream)
{
    const float* x   = (const float*)d_in[0];
    const float* Wq  = (const float*)d_in[1];
    const float* Wk  = (const float*)d_in[2];
    const float* Wv  = (const float*)d_in[3];
    const float* Wo  = (const float*)d_in[4];
    const float* rel = (const float*)d_in[5];

    float* ws   = (float*)d_ws;
    float* q    = ws;                    // [B,H,S,D]
    float* kbuf = ws + 4194304;          // [B,H,S,D]
    float* vbuf = ws + 8388608;          // [B,H,S,D]
    float* qrel = ws + 12582912;         // [B*H,S,128]
    float* ctx  = ws + 20971520;         // [B,S,H,D]

    dim3 gemm_grid(8, 32);
    sgemm128<1><<<gemm_grid, 256, 0, stream>>>(x, Wq, q);
    sgemm128<1><<<gemm_grid, 256, 0, stream>>>(x, Wk, kbuf);
    sgemm128<1><<<gemm_grid, 256, 0, stream>>>(x, Wv, vbuf);
    rope_kernel<<<16384, 256, 0, stream>>>(q, kbuf);
    qrel_kernel<<<dim3(32, 32), 256, 0, stream>>>(q, rel, qrel);
    flash_kernel<<<1024, 256, 0, stream>>>(q, kbuf, vbuf, qrel, ctx);
    sgemm128<0><<<gemm_grid, 256, 0, stream>>>(ctx, Wo, (float*)d_out);
}

// Round 5
// 3157.487 us; speedup vs baseline: 2.8818x; 1.4604x over previous
//
#include <hip/hip_runtime.h>
#include <hip/hip_bf16.h>
#include <math.h>

// Problem constants: B=2, S=2048, E=1024, H=16, D=64, buckets used: 0..127 (causal => rel>=0)

static __device__ __forceinline__ unsigned short f2bf(float x) {
    unsigned u = __float_as_uint(x);
    unsigned r = (u + 0x7fffu + ((u >> 16) & 1u)) >> 16;   // RNE
    return (unsigned short)r;
}
static __device__ __forceinline__ float bf2f(unsigned short h) {
    return __uint_as_float(((unsigned)h) << 16);
}

// async 16B global->LDS (wave-uniform LDS base + lane*16, so LDS layout must be linear)
#define GLOAD16(gp, lp)                                                            \
    __builtin_amdgcn_global_load_lds(                                              \
        (const __attribute__((address_space(1))) unsigned int*)(gp),               \
        (__attribute__((address_space(3))) unsigned int*)(lp), 16, 0, 0)

// ---------------- SGEMM 128x128 tile, K-step 16, fp32 ----------------
// MODE 0: C[m*1024+n] plain row-major   MODE 1: scatter to [B,H,S,D] head layout
template<int MODE>
__global__ void sgemm128(const float* __restrict__ A, const float* __restrict__ W,
                         float* __restrict__ C)
{
    __shared__ float As[16*128];   // As[k][m]
    __shared__ float Bs[16*128];   // Bs[k][n]
    const int tid = threadIdx.x;
    const int tx = tid & 15, ty = tid >> 4;
    const int bx = blockIdx.x, by = blockIdx.y;
    const int arow = tid >> 1;          // 0..127
    const int acol = (tid & 1) * 8;     // 0 or 8
    const int brow = tid >> 4;          // 0..15
    const int bcol = (tid & 15) * 8;    // 0..120

    float acc[8][8];
#pragma unroll
    for (int i = 0; i < 8; ++i)
#pragma unroll
        for (int j = 0; j < 8; ++j) acc[i][j] = 0.f;

    const float* ap = A + (size_t)(by*128 + arow)*1024 + acol;
    const float* bp = W + (size_t)brow*1024 + bx*128 + bcol;

    for (int k0 = 0; k0 < 1024; k0 += 16) {
        float4 a0 = *(const float4*)(ap + k0);
        float4 a1 = *(const float4*)(ap + k0 + 4);
        float4 b0 = *(const float4*)(bp + (size_t)k0*1024);
        float4 b1 = *(const float4*)(bp + (size_t)k0*1024 + 4);
        As[(acol+0)*128 + arow] = a0.x;
        As[(acol+1)*128 + arow] = a0.y;
        As[(acol+2)*128 + arow] = a0.z;
        As[(acol+3)*128 + arow] = a0.w;
        As[(acol+4)*128 + arow] = a1.x;
        As[(acol+5)*128 + arow] = a1.y;
        As[(acol+6)*128 + arow] = a1.z;
        As[(acol+7)*128 + arow] = a1.w;
        *(float4*)&Bs[brow*128 + bcol]     = b0;
        *(float4*)&Bs[brow*128 + bcol + 4] = b1;
        __syncthreads();
#pragma unroll
        for (int kk = 0; kk < 16; ++kk) {
            float a[8], b[8];
            *(float4*)&a[0] = *(const float4*)&As[kk*128 + ty*8];
            *(float4*)&a[4] = *(const float4*)&As[kk*128 + ty*8 + 4];
            *(float4*)&b[0] = *(const float4*)&Bs[kk*128 + tx*8];
            *(float4*)&b[4] = *(const float4*)&Bs[kk*128 + tx*8 + 4];
#pragma unroll
            for (int i = 0; i < 8; ++i)
#pragma unroll
                for (int j = 0; j < 8; ++j)
                    acc[i][j] = fmaf(a[i], b[j], acc[i][j]);
        }
        __syncthreads();
    }
    const int n0 = bx*128 + tx*8;
#pragma unroll
    for (int i = 0; i < 8; ++i) {
        const int m = by*128 + ty*8 + i;
        float4 st0 = make_float4(acc[i][0], acc[i][1], acc[i][2], acc[i][3]);
        float4 st1 = make_float4(acc[i][4], acc[i][5], acc[i][6], acc[i][7]);
        if (MODE == 0) {
            float* o = C + (size_t)m*1024 + n0;
            *(float4*)o     = st0;
            *(float4*)(o+4) = st1;
        } else {
            const int bb = m >> 11, ss = m & 2047;
            const int hh = n0 >> 6, dd = n0 & 63;   // 8-col chunk never crosses a head
            float* o = C + ((((size_t)bb*16 + hh)*2048 + ss)*64 + dd);
            *(float4*)o     = st0;
            *(float4*)(o+4) = st1;
        }
    }
}

// ---------------- RoPE (in place on q and k, [B,H,S,D]) ----------------
__global__ void rope_kernel(float* __restrict__ q, float* __restrict__ k)
{
    const int t = blockIdx.x * 256 + threadIdx.x;    // 0 .. 2^22-1
    const int ten = t >> 21;                         // 0:q 1:k
    const int r = t & ((1 << 21) - 1);
    const int dd = r & 31;                           // low half element
    const int s  = (r >> 5) & 2047;
    const int bh = r >> 16;                          // 0..31
    float* p = ten ? k : q;
    const size_t base = ((size_t)bh*2048 + s)*64;
    const float x0 = p[base + dd];
    const float x1 = p[base + dd + 32];
    const float f0 = (float)(dd >> 1);
    const float CC = 0.41524101186092029f;           // log2(10000)/32
    const float if0 = exp2f(-f0 * CC);
    const float if1 = exp2f(-(f0 + 16.f) * CC);
    const float a0 = (float)s * if0;
    const float a1 = (float)s * if1;
    p[base + dd]      = x0 * cosf(a0) - x1 * sinf(a0);
    p[base + dd + 32] = x1 * cosf(a1) + x0 * sinf(a1);
}

// ---------------- q_rel = q . rel_emb  ->  [B*H, S, 128] ----------------
__global__ void qrel_kernel(const float* __restrict__ q, const float* __restrict__ rel_emb,
                            float* __restrict__ qrel)
{
    __shared__ float qs[64*65];
    __shared__ float rls[128*64];
    const int tid = threadIdx.x;
    const int s0 = blockIdx.x * 64;
    const int bh = blockIdx.y;
    const int h  = bh & 15;

    for (int idx = tid; idx < 64*16; idx += 256) {
        int r = idx >> 4, c4 = (idx & 15) << 2;
        float4 vv = *(const float4*)(q + ((size_t)bh*2048 + s0 + r)*64 + c4);
        qs[r*65 + c4 + 0] = vv.x;
        qs[r*65 + c4 + 1] = vv.y;
        qs[r*65 + c4 + 2] = vv.z;
        qs[r*65 + c4 + 3] = vv.w;
    }
    for (int idx = tid; idx < 128*16; idx += 256) {
        int n = idx >> 4, c4 = (idx & 15) << 2;
        *(float4*)&rls[n*64 + c4] = *(const float4*)(rel_emb + ((size_t)n*16 + h)*64 + c4);
    }
    __syncthreads();

    const int r  = tid & 63;
    const int nb = tid >> 6;
    float* orow = qrel + ((size_t)bh*2048 + s0 + r)*128;
#pragma unroll 1
    for (int kq = 0; kq < 8; ++kq) {
        const int n0 = nb*4 + kq*16;
        float a0 = 0.f, a1 = 0.f, a2 = 0.f, a3 = 0.f;
#pragma unroll
        for (int d = 0; d < 64; ++d) {
            const float qv = qs[r*65 + d];
            a0 = fmaf(qv, rls[(n0+0)*64 + d], a0);
            a1 = fmaf(qv, rls[(n0+1)*64 + d], a1);
            a2 = fmaf(qv, rls[(n0+2)*64 + d], a2);
            a3 = fmaf(qv, rls[(n0+3)*64 + d], a3);
        }
        float4 st = make_float4(a0, a1, a2, a3);
        *(float4*)&orow[n0] = st;
    }
}

// ---------------- causal flash attention, 256 thr / 4 waves / 64 q-rows ----------------
// 4 lanes per q-row (16 dims each). K/V 32x64 tiles staged via global_load_lds (linear),
// processed as two 16-row online-softmax sub-steps (sv[16] keeps VGPR < 128, no spill).
// LDS = 2*8192 + 64*132*2 = 33280 B; 4 blocks/CU, all 1024 blocks resident.
__global__ __launch_bounds__(256, 2) void flash_kernel(
    const float* __restrict__ q, const float* __restrict__ k,
    const float* __restrict__ v, const float* __restrict__ qrel,
    float* __restrict__ ctx)
{
    __shared__ float kls[32*64];
    __shared__ float vls[32*64];
    __shared__ unsigned short qrels[64*132];   // bf16 bias rows, pad 132

    const int tid = threadIdx.x;
    const int id  = blockIdx.x;
    const int bh  = id & 31;                   // all blocks of a head -> same XCD (id%8 fixed)
    const int m   = id >> 5;
    const int a   = m & 7, b = m >> 3;
    const int bx  = 8*b + ((b & 1) ? 7 - a : a);   // bijection; per-CU tile-work ~constant
    const int i0  = bx * 64;

    const int wave = tid >> 6;
    const int lane = tid & 63;
    const int row  = wave*16 + (lane >> 2);    // local q-row 0..63
    const int c    = lane & 3;                 // dim chunk: c*16 .. c*16+15
    const int i    = i0 + row;

    // stage bias rows (fp32 global -> bf16 LDS)
    for (int idx = tid; idx < 64*32; idx += 256) {
        const int r  = idx >> 5;
        const int c4 = (idx & 31) << 2;
        float4 vv = *(const float4*)(qrel + ((size_t)bh*2048 + i0 + r)*128 + c4);
        unsigned short* dst = &qrels[r*132 + c4];
        dst[0] = f2bf(vv.x); dst[1] = f2bf(vv.y);
        dst[2] = f2bf(vv.z); dst[3] = f2bf(vv.w);
    }

    // q fragment: 16 dims
    float qreg[16];
    {
        const float* qrow = q + ((size_t)bh*2048 + i)*64 + c*16;
#pragma unroll
        for (int cc = 0; cc < 4; ++cc) {
            float4 vv = ((const float4*)qrow)[cc];
            qreg[4*cc+0] = vv.x; qreg[4*cc+1] = vv.y;
            qreg[4*cc+2] = vv.z; qreg[4*cc+3] = vv.w;
        }
    }
    float acc[16];
#pragma unroll
    for (int d = 0; d < 16; ++d) acc[d] = 0.f;
    float mrun = -INFINITY, lsum = 0.f;

    // staging: wave 0,1 -> K rows 0-15/16-31 ; wave 2,3 -> V. One 8KB tile = 4 wave-loads each.
    const char* gbase = (const char*)(((wave < 2) ? k : v) + (size_t)bh*2048*64)
                        + ((wave & 1) * 4096 + lane * 16);
    char* lbase = (char*)((wave < 2) ? kls : vls) + ((wave & 1) * 4096 + lane * 16);

    const int ntiles = (i0 >> 5) + 2;
    const float SCL = 0.1803368801111204f;   // (1/8) * log2(e); exp2-based softmax

    for (int t = 0; t < ntiles; ++t) {
        const int j0 = t * 32;
        __syncthreads();                      // prev tile consumed (t=0: qrels staged)
        {
            const char* g = gbase + (size_t)j0 * 256;
            GLOAD16(g + 0,    lbase + 0);
            GLOAD16(g + 1024, lbase + 1024);
            GLOAD16(g + 2048, lbase + 2048);
            GLOAD16(g + 3072, lbase + 3072);
        }
        __syncthreads();                      // vmcnt drained -> tile visible

#pragma unroll
        for (int hlf = 0; hlf < 2; ++hlf) {
            const int jb = j0 + hlf*16;
            float sv[16];
            float tmax = -INFINITY;
#pragma unroll
            for (int kk = 0; kk < 16; ++kk) {
                const float4* kr = (const float4*)&kls[(hlf*16 + kk)*64 + c*16];
                float dot = 0.f;
#pragma unroll
                for (int cc = 0; cc < 4; ++cc) {
                    float4 kv = kr[cc];
                    dot = fmaf(qreg[4*cc+0], kv.x, dot);
                    dot = fmaf(qreg[4*cc+1], kv.y, dot);
                    dot = fmaf(qreg[4*cc+2], kv.z, dot);
                    dot = fmaf(qreg[4*cc+3], kv.w, dot);
                }
                dot += __shfl_xor(dot, 1);
                dot += __shfl_xor(dot, 2);
                const int rel = i - (jb + kk);
                int bkt;
                if (rel < 64) {
                    bkt = (rel < 0) ? 0 : rel;
                } else {
                    bkt = 64 + (int)(__log2f((float)rel) * 8.0f - 48.0f);
                    bkt = bkt > 127 ? 127 : bkt;
                }
                const float bias = bf2f(qrels[row*132 + bkt]);
                const float sfull = (dot + bias) * SCL;
                sv[kk] = (rel >= 0) ? sfull : -1e30f;
                tmax = fmaxf(tmax, sv[kk]);
            }
            const float newm = fmaxf(mrun, tmax);
            const float corr = exp2f(mrun - newm);   // exp2(-inf)=0 on first half-tile
            lsum *= corr;
#pragma unroll
            for (int d = 0; d < 16; ++d) acc[d] *= corr;
#pragma unroll
            for (int kk = 0; kk < 16; ++kk) {
                const float p = exp2f(sv[kk] - newm);
                lsum += p;
                const float4* vr = (const float4*)&vls[(hlf*16 + kk)*64 + c*16];
#pragma unroll
                for (int cc = 0; cc < 4; ++cc) {
                    float4 vv = vr[cc];
                    acc[4*cc+0] = fmaf(p, vv.x, acc[4*cc+0]);
                    acc[4*cc+1] = fmaf(p, vv.y, acc[4*cc+1]);
                    acc[4*cc+2] = fmaf(p, vv.z, acc[4*cc+2]);
                    acc[4*cc+3] = fmaf(p, vv.w, acc[4*cc+3]);
                }
            }
            mrun = newm;
        }
    }

    const float inv = 1.0f / lsum;
    // ctx layout [B,S,H,D]
    float* orow = ctx + ((((size_t)(bh >> 4))*2048 + i)*16 + (bh & 15))*64 + c*16;
#pragma unroll
    for (int cc = 0; cc < 4; ++cc) {
        float4 st = make_float4(acc[4*cc+0]*inv, acc[4*cc+1]*inv,
                                acc[4*cc+2]*inv, acc[4*cc+3]*inv);
        ((float4*)orow)[cc] = st;
    }
}

extern "C" void kernel_launch(void* const* d_in, const int* in_sizes, int n_in,
                              void* d_out, int out_size, void* d_ws, size_t ws_size,
                              hipStream_t stream)
{
    const float* x   = (const float*)d_in[0];
    const float* Wq  = (const float*)d_in[1];
    const float* Wk  = (const float*)d_in[2];
    const float* Wv  = (const float*)d_in[3];
    const float* Wo  = (const float*)d_in[4];
    const float* rel = (const float*)d_in[5];

    float* ws   = (float*)d_ws;
    float* q    = ws;                    // [B,H,S,D]
    float* kbuf = ws + 4194304;          // [B,H,S,D]
    float* vbuf = ws + 8388608;          // [B,H,S,D]
    float* qrel = ws + 12582912;         // [B*H,S,128]
    float* ctx  = ws + 20971520;         // [B,S,H,D]

    dim3 gemm_grid(8, 32);
    sgemm128<1><<<gemm_grid, 256, 0, stream>>>(x, Wq, q);
    sgemm128<1><<<gemm_grid, 256, 0, stream>>>(x, Wk, kbuf);
    sgemm128<1><<<gemm_grid, 256, 0, stream>>>(x, Wv, vbuf);
    rope_kernel<<<16384, 256, 0, stream>>>(q, kbuf);
    qrel_kernel<<<dim3(32, 32), 256, 0, stream>>>(q, rel, qrel);
    flash_kernel<<<1024, 256, 0, stream>>>(q, kbuf, vbuf, qrel, ctx);
    sgemm128<0><<<gemm_grid, 256, 0, stream>>>(ctx, Wo, (float*)d_out);
}

// Round 6
// 1322.723 us; speedup vs baseline: 6.8793x; 2.3871x over previous
//
#include <hip/hip_runtime.h>
#include <hip/hip_bf16.h>
#include <math.h>

// Problem constants: B=2, S=2048, E=1024, H=16, D=64, buckets used: 0..127 (causal => rel>=0)

typedef __attribute__((ext_vector_type(8))) short bf16x8;
typedef __attribute__((ext_vector_type(4))) float f32x4;

static __device__ __forceinline__ unsigned short f2bf(float x) {
    unsigned u = __float_as_uint(x);
    unsigned r = (u + 0x7fffu + ((u >> 16) & 1u)) >> 16;   // RNE
    return (unsigned short)r;
}
static __device__ __forceinline__ float bf2f(unsigned short h) {
    return __uint_as_float(((unsigned)h) << 16);
}

// async 16B global->LDS (wave-uniform LDS base + lane*16, so LDS layout must be linear)
#define GLOAD16(gp, lp)                                                            \
    __builtin_amdgcn_global_load_lds(                                              \
        (const __attribute__((address_space(1))) unsigned int*)(gp),               \
        (__attribute__((address_space(3))) unsigned int*)(lp), 16, 0, 0)

// ---------------- f32 -> bf16 convert (8 elem/thread, exact-fit grid) ----------------
__global__ void tobf16(const float* __restrict__ in, unsigned short* __restrict__ out)
{
    const size_t t = (size_t)blockIdx.x * 256 + threadIdx.x;
    const float4* p = (const float4*)(in + t*8);
    float4 a = p[0], b = p[1];
    unsigned w0 = f2bf(a.x) | ((unsigned)f2bf(a.y) << 16);
    unsigned w1 = f2bf(a.z) | ((unsigned)f2bf(a.w) << 16);
    unsigned w2 = f2bf(b.x) | ((unsigned)f2bf(b.y) << 16);
    unsigned w3 = f2bf(b.z) | ((unsigned)f2bf(b.w) << 16);
    *(uint4*)(out + t*8) = make_uint4(w0, w1, w2, w3);
}

// ---------------- W [K=1024][N=1024] f32  ->  Wt [N][K] bf16 (64x64 LDS tiles) ----------------
__global__ void transp_bf(const float* __restrict__ W, unsigned short* __restrict__ Wt)
{
    __shared__ unsigned short tls[64][65];
    const int tid = threadIdx.x;
    const int bxt = blockIdx.x & 15;   // n-tile
    const int byt = blockIdx.x >> 4;   // k-tile
    const int r   = tid >> 2;          // 0..63
    const int c0  = (tid & 3) * 16;    // 0/16/32/48
    const float* src = W + (size_t)(byt*64 + r)*1024 + bxt*64 + c0;
#pragma unroll
    for (int j = 0; j < 4; ++j) {
        float4 vv = ((const float4*)src)[j];
        tls[c0 + j*4 + 0][r] = f2bf(vv.x);
        tls[c0 + j*4 + 1][r] = f2bf(vv.y);
        tls[c0 + j*4 + 2][r] = f2bf(vv.z);
        tls[c0 + j*4 + 3][r] = f2bf(vv.w);
    }
    __syncthreads();
    unsigned short* dst = Wt + (size_t)(bxt*64 + r)*1024 + byt*64 + c0;
    unsigned w[8];
#pragma unroll
    for (int j = 0; j < 8; ++j)
        w[j] = (unsigned)tls[r][c0 + 2*j] | ((unsigned)tls[r][c0 + 2*j + 1] << 16);
    *(uint4*)(dst)     = make_uint4(w[0], w[1], w[2], w[3]);
    *(uint4*)(dst + 8) = make_uint4(w[4], w[5], w[6], w[7]);
}

// ---------------- bf16 MFMA GEMM: C[M=4096][N=1024] = A[M][K=1024] * Bt[N][K]^T ----------------
// 128x128 tile, 4 waves (2x2 of 64x64), BK=64, double-buffered LDS, global_load_lds staging.
// MODE 0: C row-major   MODE 1: scatter to [B,H,S,D] head layout
template<int MODE>
__global__ __launch_bounds__(256) void gemm_bt(const unsigned short* __restrict__ A,
                                               const unsigned short* __restrict__ Bt,
                                               float* __restrict__ C)
{
    __shared__ __align__(16) unsigned short Als[2][8192];   // [buf][row*64 + k]
    __shared__ __align__(16) unsigned short Bls[2][8192];   // [buf][col*64 + k]
    const int tid  = threadIdx.x;
    const int wave = tid >> 6, lane = tid & 63;
    const int wr = (wave >> 1) * 64, wc = (wave & 1) * 64;
    const int bx = blockIdx.x, by = blockIdx.y;

    const int srow = tid >> 3;            // staging row-in-32-chunk
    const unsigned short* agp = A  + (size_t)(by*128)*1024 + (tid & 7)*8;
    const unsigned short* bgp = Bt + (size_t)(bx*128)*1024 + (tid & 7)*8;

    f32x4 acc[4][4];
#pragma unroll
    for (int m = 0; m < 4; ++m)
#pragma unroll
        for (int n = 0; n < 4; ++n) acc[m][n] = (f32x4)0.f;

#define STAGE(t, buf)                                                                  \
    {                                                                                  \
        const int k0s = (t) * 64;                                                      \
        _Pragma("unroll")                                                              \
        for (int j = 0; j < 4; ++j) {                                                  \
            GLOAD16(agp + (size_t)(j*32 + srow)*1024 + k0s, &Als[buf][0] + j*2048 + tid*8); \
            GLOAD16(bgp + (size_t)(j*32 + srow)*1024 + k0s, &Bls[buf][0] + j*2048 + tid*8); \
        }                                                                              \
    }

#define COMPUTE(buf)                                                                   \
    {                                                                                  \
        _Pragma("unroll")                                                              \
        for (int ks = 0; ks < 2; ++ks) {                                               \
            bf16x8 af[4], bfr[4];                                                      \
            _Pragma("unroll")                                                          \
            for (int m = 0; m < 4; ++m)                                                \
                af[m] = *(const bf16x8*)&Als[buf][(wr + m*16 + (lane & 15))*64 + ks*32 + (lane >> 4)*8]; \
            _Pragma("unroll")                                                          \
            for (int n = 0; n < 4; ++n)                                                \
                bfr[n] = *(const bf16x8*)&Bls[buf][(wc + n*16 + (lane & 15))*64 + ks*32 + (lane >> 4)*8]; \
            _Pragma("unroll")                                                          \
            for (int m = 0; m < 4; ++m)                                                \
                _Pragma("unroll")                                                      \
                for (int n = 0; n < 4; ++n)                                            \
                    acc[m][n] = __builtin_amdgcn_mfma_f32_16x16x32_bf16(af[m], bfr[n], acc[m][n], 0, 0, 0); \
        }                                                                              \
    }

    STAGE(0, 0);
    __syncthreads();                     // vmcnt(0) drain + barrier: tile 0 ready
    int cur = 0;
    for (int t = 0; t < 16; ++t) {
        if (t < 15) STAGE(t + 1, cur ^ 1);   // issue next-tile loads before compute
        COMPUTE(cur);
        __syncthreads();                 // drains next-tile vmcnt + barrier
        cur ^= 1;
    }
#undef STAGE
#undef COMPUTE

#pragma unroll
    for (int m = 0; m < 4; ++m) {
        const int r0 = by*128 + wr + m*16 + (lane >> 4)*4;
#pragma unroll
        for (int n = 0; n < 4; ++n) {
            const int col = bx*128 + wc + n*16 + (lane & 15);
#pragma unroll
            for (int rg = 0; rg < 4; ++rg) {
                const int row = r0 + rg;
                const float val = acc[m][n][rg];
                if (MODE == 0) {
                    C[(size_t)row*1024 + col] = val;
                } else {
                    const int bb = row >> 11, ss = row & 2047;
                    const int hh = col >> 6,  dd = col & 63;
                    C[(((size_t)bb*16 + hh)*2048 + ss)*64 + dd] = val;
                }
            }
        }
    }
}

// ---------------- RoPE (in place on q and k, [B,H,S,D]) ----------------
__global__ void rope_kernel(float* __restrict__ q, float* __restrict__ k)
{
    const int t = blockIdx.x * 256 + threadIdx.x;    // 0 .. 2^22-1
    const int ten = t >> 21;                         // 0:q 1:k
    const int r = t & ((1 << 21) - 1);
    const int dd = r & 31;                           // low half element
    const int s  = (r >> 5) & 2047;
    const int bh = r >> 16;                          // 0..31
    float* p = ten ? k : q;
    const size_t base = ((size_t)bh*2048 + s)*64;
    const float x0 = p[base + dd];
    const float x1 = p[base + dd + 32];
    const float f0 = (float)(dd >> 1);
    const float CC = 0.41524101186092029f;           // log2(10000)/32
    const float if0 = exp2f(-f0 * CC);
    const float if1 = exp2f(-(f0 + 16.f) * CC);
    const float a0 = (float)s * if0;
    const float a1 = (float)s * if1;
    p[base + dd]      = x0 * cosf(a0) - x1 * sinf(a0);
    p[base + dd + 32] = x1 * cosf(a1) + x0 * sinf(a1);
}

// ---------------- q_rel = q . rel_emb  ->  [B*H, S, 128] ----------------
__global__ void qrel_kernel(const float* __restrict__ q, const float* __restrict__ rel_emb,
                            float* __restrict__ qrel)
{
    __shared__ float qs[64*65];
    __shared__ float rls[128*64];
    const int tid = threadIdx.x;
    const int s0 = blockIdx.x * 64;
    const int bh = blockIdx.y;
    const int h  = bh & 15;

    for (int idx = tid; idx < 64*16; idx += 256) {
        int r = idx >> 4, c4 = (idx & 15) << 2;
        float4 vv = *(const float4*)(q + ((size_t)bh*2048 + s0 + r)*64 + c4);
        qs[r*65 + c4 + 0] = vv.x;
        qs[r*65 + c4 + 1] = vv.y;
        qs[r*65 + c4 + 2] = vv.z;
        qs[r*65 + c4 + 3] = vv.w;
    }
    for (int idx = tid; idx < 128*16; idx += 256) {
        int n = idx >> 4, c4 = (idx & 15) << 2;
        *(float4*)&rls[n*64 + c4] = *(const float4*)(rel_emb + ((size_t)n*16 + h)*64 + c4);
    }
    __syncthreads();

    const int r  = tid & 63;
    const int nb = tid >> 6;
    float* orow = qrel + ((size_t)bh*2048 + s0 + r)*128;
#pragma unroll 1
    for (int kq = 0; kq < 8; ++kq) {
        const int n0 = nb*4 + kq*16;
        float a0 = 0.f, a1 = 0.f, a2 = 0.f, a3 = 0.f;
#pragma unroll
        for (int d = 0; d < 64; ++d) {
            const float qv = qs[r*65 + d];
            a0 = fmaf(qv, rls[(n0+0)*64 + d], a0);
            a1 = fmaf(qv, rls[(n0+1)*64 + d], a1);
            a2 = fmaf(qv, rls[(n0+2)*64 + d], a2);
            a3 = fmaf(qv, rls[(n0+3)*64 + d], a3);
        }
        float4 st = make_float4(a0, a1, a2, a3);
        *(float4*)&orow[n0] = st;
    }
}

// ---------------- causal flash attention, 256 thr / 4 waves / 64 q-rows ----------------
// 4 lanes per q-row (16 dims each). K/V 32x64 tiles staged via global_load_lds (linear),
// two 16-row online-softmax sub-steps. NO register cap: spills cost more than occupancy.
__global__ __launch_bounds__(256) void flash_kernel(
    const float* __restrict__ q, const float* __restrict__ k,
    const float* __restrict__ v, const float* __restrict__ qrel,
    float* __restrict__ ctx)
{
    __shared__ float kls[32*64];
    __shared__ float vls[32*64];
    __shared__ unsigned short qrels[64*132];   // bf16 bias rows, pad 132

    const int tid = threadIdx.x;
    const int id  = blockIdx.x;
    const int bh  = id & 31;                   // all blocks of a head -> same XCD (id%8 fixed)
    const int m   = id >> 5;
    const int a   = m & 7, b = m >> 3;
    const int bx  = 8*b + ((b & 1) ? 7 - a : a);   // bijection; per-CU tile-work ~constant
    const int i0  = bx * 64;

    const int wave = tid >> 6;
    const int lane = tid & 63;
    const int row  = wave*16 + (lane >> 2);    // local q-row 0..63
    const int c    = lane & 3;                 // dim chunk: c*16 .. c*16+15
    const int i    = i0 + row;

    // stage bias rows (fp32 global -> bf16 LDS)
    for (int idx = tid; idx < 64*32; idx += 256) {
        const int r  = idx >> 5;
        const int c4 = (idx & 31) << 2;
        float4 vv = *(const float4*)(qrel + ((size_t)bh*2048 + i0 + r)*128 + c4);
        unsigned short* dst = &qrels[r*132 + c4];
        dst[0] = f2bf(vv.x); dst[1] = f2bf(vv.y);
        dst[2] = f2bf(vv.z); dst[3] = f2bf(vv.w);
    }

    // q fragment: 16 dims
    float qreg[16];
    {
        const float* qrow = q + ((size_t)bh*2048 + i)*64 + c*16;
#pragma unroll
        for (int cc = 0; cc < 4; ++cc) {
            float4 vv = ((const float4*)qrow)[cc];
            qreg[4*cc+0] = vv.x; qreg[4*cc+1] = vv.y;
            qreg[4*cc+2] = vv.z; qreg[4*cc+3] = vv.w;
        }
    }
    float acc[16];
#pragma unroll
    for (int d = 0; d < 16; ++d) acc[d] = 0.f;
    float mrun = -INFINITY, lsum = 0.f;

    // staging: wave 0,1 -> K rows 0-15/16-31 ; wave 2,3 -> V.
    const char* gbase = (const char*)(((wave < 2) ? k : v) + (size_t)bh*2048*64)
                        + ((wave & 1) * 4096 + lane * 16);
    char* lbase = (char*)((wave < 2) ? kls : vls) + ((wave & 1) * 4096 + lane * 16);

    const int ntiles = (i0 >> 5) + 2;
    const float SCL = 0.1803368801111204f;   // (1/8) * log2(e); exp2-based softmax

    for (int t = 0; t < ntiles; ++t) {
        const int j0 = t * 32;
        __syncthreads();                      // prev tile consumed (t=0: qrels staged)
        {
            const char* g = gbase + (size_t)j0 * 256;
            GLOAD16(g + 0,    lbase + 0);
            GLOAD16(g + 1024, lbase + 1024);
            GLOAD16(g + 2048, lbase + 2048);
            GLOAD16(g + 3072, lbase + 3072);
        }
        __syncthreads();                      // vmcnt drained -> tile visible

#pragma unroll
        for (int hlf = 0; hlf < 2; ++hlf) {
            const int jb = j0 + hlf*16;
            float sv[16];
            float tmax = -INFINITY;
#pragma unroll
            for (int kk = 0; kk < 16; ++kk) {
                const float4* kr = (const float4*)&kls[(hlf*16 + kk)*64 + c*16];
                float dot = 0.f;
#pragma unroll
                for (int cc = 0; cc < 4; ++cc) {
                    float4 kv = kr[cc];
                    dot = fmaf(qreg[4*cc+0], kv.x, dot);
                    dot = fmaf(qreg[4*cc+1], kv.y, dot);
                    dot = fmaf(qreg[4*cc+2], kv.z, dot);
                    dot = fmaf(qreg[4*cc+3], kv.w, dot);
                }
                dot += __shfl_xor(dot, 1);
                dot += __shfl_xor(dot, 2);
                const int rel = i - (jb + kk);
                int bkt;
                if (rel < 64) {
                    bkt = (rel < 0) ? 0 : rel;
                } else {
                    bkt = 64 + (int)(__log2f((float)rel) * 8.0f - 48.0f);
                    bkt = bkt > 127 ? 127 : bkt;
                }
                const float bias = bf2f(qrels[row*132 + bkt]);
                const float sfull = (dot + bias) * SCL;
                sv[kk] = (rel >= 0) ? sfull : -1e30f;
                tmax = fmaxf(tmax, sv[kk]);
            }
            const float newm = fmaxf(mrun, tmax);
            const float corr = exp2f(mrun - newm);   // exp2(-inf)=0 on first half-tile
            lsum *= corr;
#pragma unroll
            for (int d = 0; d < 16; ++d) acc[d] *= corr;
#pragma unroll
            for (int kk = 0; kk < 16; ++kk) {
                const float p = exp2f(sv[kk] - newm);
                lsum += p;
                const float4* vr = (const float4*)&vls[(hlf*16 + kk)*64 + c*16];
#pragma unroll
                for (int cc = 0; cc < 4; ++cc) {
                    float4 vv = vr[cc];
                    acc[4*cc+0] = fmaf(p, vv.x, acc[4*cc+0]);
                    acc[4*cc+1] = fmaf(p, vv.y, acc[4*cc+1]);
                    acc[4*cc+2] = fmaf(p, vv.z, acc[4*cc+2]);
                    acc[4*cc+3] = fmaf(p, vv.w, acc[4*cc+3]);
                }
            }
            mrun = newm;
        }
    }

    const float inv = 1.0f / lsum;
    // ctx layout [B,S,H,D]
    float* orow = ctx + ((((size_t)(bh >> 4))*2048 + i)*16 + (bh & 15))*64 + c*16;
#pragma unroll
    for (int cc = 0; cc < 4; ++cc) {
        float4 st = make_float4(acc[4*cc+0]*inv, acc[4*cc+1]*inv,
                                acc[4*cc+2]*inv, acc[4*cc+3]*inv);
        ((float4*)orow)[cc] = st;
    }
}

extern "C" void kernel_launch(void* const* d_in, const int* in_sizes, int n_in,
                              void* d_out, int out_size, void* d_ws, size_t ws_size,
                              hipStream_t stream)
{
    const float* x   = (const float*)d_in[0];
    const float* Wq  = (const float*)d_in[1];
    const float* Wk  = (const float*)d_in[2];
    const float* Wv  = (const float*)d_in[3];
    const float* Wo  = (const float*)d_in[4];
    const float* rel = (const float*)d_in[5];

    float* ws   = (float*)d_ws;
    float* q    = ws;                    // [B,H,S,D]   4M f
    float* kbuf = ws + 4194304;          // [B,H,S,D]
    float* vbuf = ws + 8388608;          // [B,H,S,D]
    float* qrel = ws + 12582912;         // [B*H,S,128] 8.39M f
    float* ctx  = ws + 20971520;         // [B,S,H,D]   4M f (ws total 96 MB)

    // transient bf16 buffers inside dead regions:
    unsigned short* xb  = (unsigned short*)(ws + 12582912);            // in qrel region (dead until qrel_kernel)
    unsigned short* wtq = (unsigned short*)(ws + 12582912 + 2097152);
    unsigned short* wtk = wtq + 1048576;
    unsigned short* wtv = wtk + 1048576;

    tobf16<<<2048, 256, 0, stream>>>(x, xb);
    transp_bf<<<256, 256, 0, stream>>>(Wq, wtq);
    transp_bf<<<256, 256, 0, stream>>>(Wk, wtk);
    transp_bf<<<256, 256, 0, stream>>>(Wv, wtv);

    dim3 gemm_grid(8, 32);
    gemm_bt<1><<<gemm_grid, 256, 0, stream>>>(xb, wtq, q);
    gemm_bt<1><<<gemm_grid, 256, 0, stream>>>(xb, wtk, kbuf);
    gemm_bt<1><<<gemm_grid, 256, 0, stream>>>(xb, wtv, vbuf);
    rope_kernel<<<16384, 256, 0, stream>>>(q, kbuf);
    qrel_kernel<<<dim3(32, 32), 256, 0, stream>>>(q, rel, qrel);
    flash_kernel<<<1024, 256, 0, stream>>>(q, kbuf, vbuf, qrel, ctx);

    // q region dead after flash: reuse for ctx-bf16 + Wo^T
    unsigned short* ctxb = (unsigned short*)ws;
    unsigned short* wto  = (unsigned short*)(ws + 2097152);
    tobf16<<<2048, 256, 0, stream>>>(ctx, ctxb);
    transp_bf<<<256, 256, 0, stream>>>(Wo, wto);
    gemm_bt<0><<<gemm_grid, 256, 0, stream>>>(ctxb, wto, (float*)d_out);
}

// Round 9
// 347.309 us; speedup vs baseline: 26.1996x; 3.8085x over previous
//
#include <hip/hip_runtime.h>
#include <hip/hip_bf16.h>
#include <math.h>

// Problem constants: B=2, S=2048, E=1024, H=16, D=64, buckets 0..127 (causal => rel>=0)

typedef __attribute__((ext_vector_type(8))) short bf16x8;
typedef __attribute__((ext_vector_type(4))) float f32x4;

static __device__ __forceinline__ unsigned short f2bf(float x) {
    unsigned u = __float_as_uint(x);
    unsigned r = (u + 0x7fffu + ((u >> 16) & 1u)) >> 16;   // RNE
    return (unsigned short)r;
}
static __device__ __forceinline__ float bf2f(unsigned short h) {
    return __uint_as_float(((unsigned)h) << 16);
}

// async 16B global->LDS (HW uses wave-uniform LDS base + lane*16 -> dest must be linear)
#define GLOAD16(gp, lp)                                                            \
    __builtin_amdgcn_global_load_lds(                                              \
        (const __attribute__((address_space(1))) unsigned int*)(gp),               \
        (__attribute__((address_space(3))) unsigned int*)(lp), 16, 0, 0)

// ---------------- f32 -> bf16 convert ----------------
__global__ void tobf16(const float* __restrict__ in, unsigned short* __restrict__ out)
{
    const size_t t = (size_t)blockIdx.x * 256 + threadIdx.x;
    const float4* p = (const float4*)(in + t*8);
    float4 a = p[0], b = p[1];
    unsigned w0 = f2bf(a.x) | ((unsigned)f2bf(a.y) << 16);
    unsigned w1 = f2bf(a.z) | ((unsigned)f2bf(a.w) << 16);
    unsigned w2 = f2bf(b.x) | ((unsigned)f2bf(b.y) << 16);
    unsigned w3 = f2bf(b.z) | ((unsigned)f2bf(b.w) << 16);
    *(uint4*)(out + t*8) = make_uint4(w0, w1, w2, w3);
}

// ---------------- W [K=1024][N=1024] f32 -> Wt [N][K] bf16 ----------------
__global__ void transp_bf(const float* __restrict__ W, unsigned short* __restrict__ Wt)
{
    __shared__ unsigned short tls[64][65];
    const int tid = threadIdx.x;
    const int bxt = blockIdx.x & 15;
    const int byt = blockIdx.x >> 4;
    const int r   = tid >> 2;
    const int c0  = (tid & 3) * 16;
    const float* src = W + (size_t)(byt*64 + r)*1024 + bxt*64 + c0;
#pragma unroll
    for (int j = 0; j < 4; ++j) {
        float4 vv = ((const float4*)src)[j];
        tls[c0 + j*4 + 0][r] = f2bf(vv.x);
        tls[c0 + j*4 + 1][r] = f2bf(vv.y);
        tls[c0 + j*4 + 2][r] = f2bf(vv.z);
        tls[c0 + j*4 + 3][r] = f2bf(vv.w);
    }
    __syncthreads();
    unsigned short* dst = Wt + (size_t)(bxt*64 + r)*1024 + byt*64 + c0;
    unsigned w[8];
#pragma unroll
    for (int j = 0; j < 8; ++j)
        w[j] = (unsigned)tls[r][c0 + 2*j] | ((unsigned)tls[r][c0 + 2*j + 1] << 16);
    *(uint4*)(dst)     = make_uint4(w[0], w[1], w[2], w[3]);
    *(uint4*)(dst + 8) = make_uint4(w[4], w[5], w[6], w[7]);
}

// ---------------- bf16 MFMA GEMM: C = A[4096][1024] * Bt[1024][1024]^T ----------------
// MODE 0: fp32 row-major  MODE 1: fp32 scatter [B,H,S,D]  MODE 2: bf16 vT [B,H,D,S]
template<int MODE>
__global__ __launch_bounds__(256) void gemm_bt(const unsigned short* __restrict__ A,
                                               const unsigned short* __restrict__ Bt,
                                               float* __restrict__ C)
{
    __shared__ __align__(16) unsigned short Als[2][8192];
    __shared__ __align__(16) unsigned short Bls[2][8192];
    const int tid  = threadIdx.x;
    const int wave = tid >> 6, lane = tid & 63;
    const int wr = (wave >> 1) * 64, wc = (wave & 1) * 64;
    const int bx = blockIdx.x, by = blockIdx.y;

    const int srow = tid >> 3;
    const unsigned short* agp = A  + (size_t)(by*128)*1024 + (tid & 7)*8;
    const unsigned short* bgp = Bt + (size_t)(bx*128)*1024 + (tid & 7)*8;

    f32x4 acc[4][4];
#pragma unroll
    for (int m = 0; m < 4; ++m)
#pragma unroll
        for (int n = 0; n < 4; ++n) acc[m][n] = (f32x4)0.f;

#define STAGE(t, buf)                                                                  \
    {                                                                                  \
        const int k0s = (t) * 64;                                                      \
        _Pragma("unroll")                                                              \
        for (int j = 0; j < 4; ++j) {                                                  \
            GLOAD16(agp + (size_t)(j*32 + srow)*1024 + k0s, &Als[buf][0] + j*2048 + tid*8); \
            GLOAD16(bgp + (size_t)(j*32 + srow)*1024 + k0s, &Bls[buf][0] + j*2048 + tid*8); \
        }                                                                              \
    }

#define COMPUTE(buf)                                                                   \
    {                                                                                  \
        _Pragma("unroll")                                                              \
        for (int ks = 0; ks < 2; ++ks) {                                               \
            bf16x8 af[4], bfr[4];                                                      \
            _Pragma("unroll")                                                          \
            for (int m = 0; m < 4; ++m)                                                \
                af[m] = *(const bf16x8*)&Als[buf][(wr + m*16 + (lane & 15))*64 + ks*32 + (lane >> 4)*8]; \
            _Pragma("unroll")                                                          \
            for (int n = 0; n < 4; ++n)                                                \
                bfr[n] = *(const bf16x8*)&Bls[buf][(wc + n*16 + (lane & 15))*64 + ks*32 + (lane >> 4)*8]; \
            _Pragma("unroll")                                                          \
            for (int m = 0; m < 4; ++m)                                                \
                _Pragma("unroll")                                                      \
                for (int n = 0; n < 4; ++n)                                            \
                    acc[m][n] = __builtin_amdgcn_mfma_f32_16x16x32_bf16(af[m], bfr[n], acc[m][n], 0, 0, 0); \
        }                                                                              \
    }

    STAGE(0, 0);
    __syncthreads();
    int cur = 0;
    for (int t = 0; t < 16; ++t) {
        if (t < 15) STAGE(t + 1, cur ^ 1);
        COMPUTE(cur);
        __syncthreads();
        cur ^= 1;
    }
#undef STAGE
#undef COMPUTE

#pragma unroll
    for (int m = 0; m < 4; ++m) {
        const int r0 = by*128 + wr + m*16 + (lane >> 4)*4;
#pragma unroll
        for (int n = 0; n < 4; ++n) {
            const int col = bx*128 + wc + n*16 + (lane & 15);
            if (MODE == 2) {
                unsigned short* Cb = (unsigned short*)C;
                const int bb = r0 >> 11, ss = r0 & 2047;
                const int hh = col >> 6, dd = col & 63;
                unsigned r01 = f2bf(acc[m][n][0]) | ((unsigned)f2bf(acc[m][n][1]) << 16);
                unsigned r23 = f2bf(acc[m][n][2]) | ((unsigned)f2bf(acc[m][n][3]) << 16);
                *(uint2*)(Cb + (((size_t)bb*16 + hh)*64 + dd)*2048 + ss) = make_uint2(r01, r23);
            } else {
#pragma unroll
                for (int rg = 0; rg < 4; ++rg) {
                    const int row = r0 + rg;
                    const float val = acc[m][n][rg];
                    if (MODE == 0) {
                        C[(size_t)row*1024 + col] = val;
                    } else {
                        const int bb = row >> 11, ss = row & 2047;
                        const int hh = col >> 6,  dd = col & 63;
                        C[(((size_t)bb*16 + hh)*2048 + ss)*64 + dd] = val;
                    }
                }
            }
        }
    }
}

// ---------------- RoPE: fp32 q/k [B,H,S,D] -> bf16 qb/kb ----------------
__global__ void rope_bf16(const float* __restrict__ qf, const float* __restrict__ kf,
                          unsigned short* __restrict__ qb, unsigned short* __restrict__ kb)
{
    const int t = blockIdx.x * 256 + threadIdx.x;
    const int ten = t >> 21;
    const int r = t & ((1 << 21) - 1);
    const int dd = r & 31;
    const int s  = (r >> 5) & 2047;
    const int bh = r >> 16;
    const float* p = ten ? kf : qf;
    unsigned short* o = ten ? kb : qb;
    const size_t base = ((size_t)bh*2048 + s)*64;
    const float x0 = p[base + dd];
    const float x1 = p[base + dd + 32];
    const float f0 = (float)(dd >> 1);
    const float CC = 0.41524101186092029f;           // log2(10000)/32
    const float if0 = exp2f(-f0 * CC);
    const float if1 = exp2f(-(f0 + 16.f) * CC);
    const float a0 = (float)s * if0;
    const float a1 = (float)s * if1;
    o[base + dd]      = f2bf(x0 * cosf(a0) - x1 * sinf(a0));
    o[base + dd + 32] = f2bf(x1 * cosf(a1) + x0 * sinf(a1));
}

// ---------------- q_rel = q . rel_emb -> bf16 [B*H, S, 128] ----------------
__global__ void qrel_kernel(const unsigned short* __restrict__ qb, const float* __restrict__ rel_emb,
                            unsigned short* __restrict__ qrelb)
{
    __shared__ float qs[64*65];
    __shared__ float rls[128*64];
    const int tid = threadIdx.x;
    const int s0 = blockIdx.x * 64;
    const int bh = blockIdx.y;
    const int h  = bh & 15;

    for (int idx = tid; idx < 512; idx += 256) {
        int r = idx >> 3, c8 = idx & 7;
        bf16x8 vv = *(const bf16x8*)(qb + ((size_t)bh*2048 + s0 + r)*64 + c8*8);
#pragma unroll
        for (int j = 0; j < 8; ++j)
            qs[r*65 + c8*8 + j] = bf2f((unsigned short)vv[j]);
    }
    for (int idx = tid; idx < 128*16; idx += 256) {
        int n = idx >> 4, c4 = (idx & 15) << 2;
        *(float4*)&rls[n*64 + c4] = *(const float4*)(rel_emb + ((size_t)n*16 + h)*64 + c4);
    }
    __syncthreads();

    const int r  = tid & 63;
    const int nb = tid >> 6;
    unsigned short* orow = qrelb + ((size_t)bh*2048 + s0 + r)*128;
#pragma unroll 1
    for (int kq = 0; kq < 8; ++kq) {
        const int n0 = nb*4 + kq*16;
        float a0 = 0.f, a1 = 0.f, a2 = 0.f, a3 = 0.f;
#pragma unroll
        for (int d = 0; d < 64; ++d) {
            const float qv = qs[r*65 + d];
            a0 = fmaf(qv, rls[(n0+0)*64 + d], a0);
            a1 = fmaf(qv, rls[(n0+1)*64 + d], a1);
            a2 = fmaf(qv, rls[(n0+2)*64 + d], a2);
            a3 = fmaf(qv, rls[(n0+3)*64 + d], a3);
        }
        unsigned r01 = f2bf(a0) | ((unsigned)f2bf(a1) << 16);
        unsigned r23 = f2bf(a2) | ((unsigned)f2bf(a3) << 16);
        *(uint2*)(orow + n0) = make_uint2(r01, r23);
    }
}

// ---------------- MFMA causal flash attention ----------------
// 4 waves x 16 q-rows. Swapped QK^T (S^T in regs, both operands loaded contiguous ->
// element-map-immune). P^T goes through LDS: written with the HW-pinned C/D map,
// read back as contiguous bf16x8 so PV's A (V^T) and B (P^T) share the same load
// pattern and any fragment element permutation cancels (gemm_bt-equivalent safety).
__global__ __launch_bounds__(256) void flash_mfma(
    const unsigned short* __restrict__ qb, const unsigned short* __restrict__ kb,
    const unsigned short* __restrict__ vT, const unsigned short* __restrict__ qrelb,
    unsigned short* __restrict__ ctxb)
{
    __shared__ __align__(16) unsigned short kls[2048];    // 32 keys x 64 d (swizzled chunks)
    __shared__ __align__(16) unsigned short vtls[2048];   // 64 d x 32 keys (swizzled chunks)
    __shared__ __align__(16) unsigned short Pls[2*4*16*40]; // [parity][wave][q][40]
    __shared__ __align__(16) unsigned short qrels[64*136];
    __shared__ unsigned char btbl[2048];

    const int tid = threadIdx.x;
    const int id  = blockIdx.x;
    const int bh  = id & 31;
    const int mm  = id >> 5;
    const int aa  = mm & 7, bgrp = mm >> 3;
    const int bx  = 8*bgrp + ((bgrp & 1) ? 7 - aa : aa);
    const int i0  = bx * 64;

    const int w   = tid >> 6;
    const int l   = tid & 63;
    const int q15 = l & 15;
    const int g   = l >> 4;
    const int iq  = i0 + w*16 + q15;

    // bucket table (rel 0..2047)
    for (int idx = tid; idx < 2048; idx += 256) {
        int bkt;
        if (idx < 64) bkt = idx;
        else {
            bkt = 64 + (int)(__log2f((float)idx) * 8.0f - 48.0f);
            bkt = bkt > 127 ? 127 : bkt;
        }
        btbl[idx] = (unsigned char)bkt;
    }
    // stage bias rows (bf16, pad 136)
    for (int idx = tid; idx < 1024; idx += 256) {
        const int r = idx >> 4, c8 = idx & 15;
        uint4 vv = *(const uint4*)(qrelb + ((size_t)bh*2048 + i0 + r)*128 + c8*8);
        *(uint4*)&qrels[r*136 + c8*8] = vv;
    }

    // Q fragments in registers
    bf16x8 qf0, qf1;
    {
        const unsigned short* qrow = qb + ((size_t)bh*2048 + i0 + w*16 + q15)*64;
        qf0 = *(const bf16x8*)(qrow + g*8);
        qf1 = *(const bf16x8*)(qrow + 32 + g*8);
    }

    f32x4 acc[4];   // O^T: d = dblk*16 + g*4 + reg, q = q15
#pragma unroll
    for (int d = 0; d < 4; ++d) acc[d] = (f32x4)0.f;
    float mrun = -INFINITY, lsum = 0.f;

    // staging: waves 0,1 -> K (4KB), waves 2,3 -> V^T (4KB); 2 GLOAD16/thread/tile
    const size_t headoff = (size_t)bh * 2048 * 64;
    const unsigned short* src0; const unsigned short* src1;
    unsigned short* dst0; unsigned short* dst1;
    int stepElems;
    if (w < 2) {
        const int D0 = w*2048 + l*16, D1 = D0 + 1024;
        const int r0 = D0 >> 7, c0 = (D0 >> 4) & 7;
        const int r1 = D1 >> 7, c1 = (D1 >> 4) & 7;
        src0 = kb + headoff + r0*64 + ((c0 ^ (r0 & 7)) * 8);
        src1 = kb + headoff + r1*64 + ((c1 ^ (r1 & 7)) * 8);
        dst0 = (unsigned short*)((char*)kls + D0);
        dst1 = (unsigned short*)((char*)kls + D1);
        stepElems = 2048;                       // 32 key-rows * 64
    } else {
        const int D0 = (w - 2)*2048 + l*16, D1 = D0 + 1024;
        const int r0 = D0 >> 6, c0 = (D0 >> 4) & 3;
        const int r1 = D1 >> 6, c1 = (D1 >> 4) & 3;
        src0 = vT + headoff + (size_t)r0*2048 + ((c0 ^ ((r0 >> 1) & 3)) * 8);
        src1 = vT + headoff + (size_t)r1*2048 + ((c1 ^ ((r1 >> 1) & 3)) * 8);
        dst0 = (unsigned short*)((char*)vtls + D0);
        dst1 = (unsigned short*)((char*)vtls + D1);
        stepElems = 32;                         // advance 32 keys along S
    }

    const int ntiles = (i0 >> 5) + 2;
    const float SCL = 0.1803368801111204f;      // (1/8)*log2(e)
    const int wave_imax = i0 + w*16 + 15;
    const int qrow_lds = (w*16 + q15) * 136;
    unsigned short* prow0 = &Pls[(w*16 + q15) * 40];          // parity 0
    unsigned short* prow1 = &Pls[4*16*40 + (w*16 + q15) * 40]; // parity 1

    for (int t = 0; t < ntiles; ++t) {
        const int j0 = t * 32;
        __syncthreads();                        // prev tile consumed (t=0: qrels/btbl staged)
        GLOAD16(src0 + (size_t)t*stepElems, dst0);
        GLOAD16(src1 + (size_t)t*stepElems, dst1);
        __syncthreads();                        // vmcnt drained -> tile visible

        if (j0 <= wave_imax) {
            // swapped QK^T: S^T[key][q], two 16-key subtiles
            f32x4 s0 = (f32x4)0.f, s1 = (f32x4)0.f;
#pragma unroll
            for (int ks = 0; ks < 2; ++ks) {
                const int ch = ks*4 + g;
                bf16x8 k0 = *(const bf16x8*)&kls[q15*64        + ((ch ^ (q15 & 7)) * 8)];
                bf16x8 k1 = *(const bf16x8*)&kls[(16 + q15)*64 + ((ch ^ (q15 & 7)) * 8)];
                bf16x8 qq = ks ? qf1 : qf0;
                s0 = __builtin_amdgcn_mfma_f32_16x16x32_bf16(k0, qq, s0, 0, 0, 0);
                s1 = __builtin_amdgcn_mfma_f32_16x16x32_bf16(k1, qq, s1, 0, 0, 0);
            }
            // bias + mask (key = g*4 + r (+16), pinned by verified C/D layout)
            float sv[8];
#pragma unroll
            for (int r = 0; r < 4; ++r) {
                const int rel0 = iq - (j0 + g*4 + r);
                const int rel1 = rel0 - 16;
                const int bi0 = rel0 < 0 ? 0 : rel0;
                const int bi1 = rel1 < 0 ? 0 : rel1;
                const float bias0 = bf2f(qrels[qrow_lds + btbl[bi0]]);
                const float bias1 = bf2f(qrels[qrow_lds + btbl[bi1]]);
                sv[r]     = (rel0 >= 0) ? (s0[r] + bias0) * SCL : -1e30f;
                sv[4 + r] = (rel1 >= 0) ? (s1[r] + bias1) * SCL : -1e30f;
            }
            // column (q-row) max across 8 in-lane + 4 lane-groups
            float tmax = fmaxf(fmaxf(fmaxf(sv[0], sv[1]), fmaxf(sv[2], sv[3])),
                               fmaxf(fmaxf(sv[4], sv[5]), fmaxf(sv[6], sv[7])));
            tmax = fmaxf(tmax, __shfl_xor(tmax, 16));
            tmax = fmaxf(tmax, __shfl_xor(tmax, 32));
            const float newm = fmaxf(mrun, tmax);
            const float corr = exp2f(mrun - newm);
            float p[8], ps = 0.f;
#pragma unroll
            for (int r = 0; r < 8; ++r) { p[r] = exp2f(sv[r] - newm); ps += p[r]; }
            ps += __shfl_xor(ps, 16);
            ps += __shfl_xor(ps, 32);
            lsum = lsum * corr + ps;
#pragma unroll
            for (int d = 0; d < 4; ++d) {
                acc[d][0] *= corr; acc[d][1] *= corr; acc[d][2] *= corr; acc[d][3] *= corr;
            }
            mrun = newm;

            // P^T via LDS: write with C/D map (key g*4+r at short offset),
            // read back contiguous -> fragment-element-map cancels vs V^T A-frag.
            unsigned short* pb = (t & 1) ? prow1 : prow0;
            *(unsigned*)(pb + g*4)      = f2bf(p[0]) | ((unsigned)f2bf(p[1]) << 16);
            *(unsigned*)(pb + g*4 + 2)  = f2bf(p[2]) | ((unsigned)f2bf(p[3]) << 16);
            *(unsigned*)(pb + 16 + g*4) = f2bf(p[4]) | ((unsigned)f2bf(p[5]) << 16);
            *(unsigned*)(pb + 18 + g*4) = f2bf(p[6]) | ((unsigned)f2bf(p[7]) << 16);
            asm volatile("s_waitcnt lgkmcnt(0)" ::: "memory");   // intra-wave write->read fence
            __builtin_amdgcn_sched_barrier(0);                   // rule 18: pin the fence
            bf16x8 pfrag = *(const bf16x8*)(pb + g*8);           // keys g*8..g*8+7, col q15

            // PV: O^T += V^T * P^T
#pragma unroll
            for (int dblk = 0; dblk < 4; ++dblk) {
                const int d = dblk*16 + q15;
                bf16x8 vf = *(const bf16x8*)&vtls[d*32 + ((g ^ ((d >> 1) & 3)) * 8)];
                acc[dblk] = __builtin_amdgcn_mfma_f32_16x16x32_bf16(vf, pfrag, acc[dblk], 0, 0, 0);
            }
        }
    }

    const float inv = 1.0f / lsum;
    const int s  = i0 + w*16 + q15;
    const int b2 = bh >> 4, hh = bh & 15;
    unsigned short* obase = ctxb + (((size_t)b2*2048 + s)*16 + hh)*64;
#pragma unroll
    for (int dblk = 0; dblk < 4; ++dblk) {
        const int d0 = dblk*16 + g*4;
        unsigned r01 = f2bf(acc[dblk][0]*inv) | ((unsigned)f2bf(acc[dblk][1]*inv) << 16);
        unsigned r23 = f2bf(acc[dblk][2]*inv) | ((unsigned)f2bf(acc[dblk][3]*inv) << 16);
        *(uint2*)(obase + d0) = make_uint2(r01, r23);
    }
}

extern "C" void kernel_launch(void* const* d_in, const int* in_sizes, int n_in,
                              void* d_out, int out_size, void* d_ws, size_t ws_size,
                              hipStream_t stream)
{
    const float* x   = (const float*)d_in[0];
    const float* Wq  = (const float*)d_in[1];
    const float* Wk  = (const float*)d_in[2];
    const float* Wv  = (const float*)d_in[3];
    const float* Wo  = (const float*)d_in[4];
    const float* rel = (const float*)d_in[5];

    float* ws = (float*)d_ws;
    // Layout (float offsets). NOTE r7/r8 bug: qrelb is 8,388,608 bf16 = 4,194,304 floats
    // of space (32 heads * 2048 rows * 128 buckets) — was given only half, trampling vTb.
    float* qf32 = ws;                                           // 0 .. 4194304 (dead after rope)
    float* kf32 = ws + 4194304;                                 // .. 8388608   (dead after rope)
    unsigned short* qb    = (unsigned short*)(ws + 8388608);    // 4,194,304 bf16 (2M floats)
    unsigned short* kbb   = (unsigned short*)(ws + 10485760);   // 4,194,304 bf16
    unsigned short* qrelb = (unsigned short*)(ws + 12582912);   // 8,388,608 bf16 (4M floats!)
    unsigned short* vTb   = (unsigned short*)(ws + 16777216);   // 4,194,304 bf16
    unsigned short* xb    = (unsigned short*)(ws + 18874368);   // 4,194,304 bf16 (transient)
    unsigned short* wtq   = (unsigned short*)(ws + 20971520);   // 1,048,576 bf16 each
    unsigned short* wtk   = (unsigned short*)(ws + 21495808);
    unsigned short* wtv   = (unsigned short*)(ws + 22020096);
    unsigned short* wto   = (unsigned short*)(ws + 22544384);   // ends 23068672 < 25165824 OK
    unsigned short* ctxb  = (unsigned short*)ws;                // over qf32 (dead by then)

    tobf16<<<2048, 256, 0, stream>>>(x, xb);
    transp_bf<<<256, 256, 0, stream>>>(Wq, wtq);
    transp_bf<<<256, 256, 0, stream>>>(Wk, wtk);
    transp_bf<<<256, 256, 0, stream>>>(Wv, wtv);
    transp_bf<<<256, 256, 0, stream>>>(Wo, wto);

    dim3 gemm_grid(8, 32);
    gemm_bt<1><<<gemm_grid, 256, 0, stream>>>(xb, wtq, qf32);
    gemm_bt<1><<<gemm_grid, 256, 0, stream>>>(xb, wtk, kf32);
    gemm_bt<2><<<gemm_grid, 256, 0, stream>>>(xb, wtv, (float*)vTb);
    rope_bf16<<<16384, 256, 0, stream>>>(qf32, kf32, qb, kbb);
    qrel_kernel<<<dim3(32, 32), 256, 0, stream>>>(qb, rel, qrelb);
    flash_mfma<<<1024, 256, 0, stream>>>(qb, kbb, vTb, qrelb, ctxb);
    gemm_bt<0><<<gemm_grid, 256, 0, stream>>>(ctxb, wto, (float*)d_out);
}

// Round 10
// 247.669 us; speedup vs baseline: 36.7400x; 1.4023x over previous
//
#include <hip/hip_runtime.h>
#include <hip/hip_bf16.h>
#include <math.h>

// Problem constants: B=2, S=2048, E=1024, H=16, D=64, buckets 0..127 (causal => rel>=0)

typedef __attribute__((ext_vector_type(8))) short bf16x8;
typedef __attribute__((ext_vector_type(4))) float f32x4;

static __device__ __forceinline__ unsigned short f2bf(float x) {
    unsigned u = __float_as_uint(x);
    unsigned r = (u + 0x7fffu + ((u >> 16) & 1u)) >> 16;   // RNE
    return (unsigned short)r;
}
static __device__ __forceinline__ float bf2f(unsigned short h) {
    return __uint_as_float(((unsigned)h) << 16);
}

// async 16B global->LDS (HW uses wave-uniform LDS base + lane*16 -> dest must be linear)
#define GLOAD16(gp, lp)                                                            \
    __builtin_amdgcn_global_load_lds(                                              \
        (const __attribute__((address_space(1))) unsigned int*)(gp),               \
        (__attribute__((address_space(3))) unsigned int*)(lp), 16, 0, 0)

// ---------------- f32 -> bf16 convert ----------------
__global__ void tobf16(const float* __restrict__ in, unsigned short* __restrict__ out)
{
    const size_t t = (size_t)blockIdx.x * 256 + threadIdx.x;
    const float4* p = (const float4*)(in + t*8);
    float4 a = p[0], b = p[1];
    unsigned w0 = f2bf(a.x) | ((unsigned)f2bf(a.y) << 16);
    unsigned w1 = f2bf(a.z) | ((unsigned)f2bf(a.w) << 16);
    unsigned w2 = f2bf(b.x) | ((unsigned)f2bf(b.y) << 16);
    unsigned w3 = f2bf(b.z) | ((unsigned)f2bf(b.w) << 16);
    *(uint4*)(out + t*8) = make_uint4(w0, w1, w2, w3);
}

// ---------------- W [K=1024][N=1024] f32 -> Wt [N][K] bf16 ----------------
__global__ void transp_bf(const float* __restrict__ W, unsigned short* __restrict__ Wt)
{
    __shared__ unsigned short tls[64][65];
    const int tid = threadIdx.x;
    const int bxt = blockIdx.x & 15;
    const int byt = blockIdx.x >> 4;
    const int r   = tid >> 2;
    const int c0  = (tid & 3) * 16;
    const float* src = W + (size_t)(byt*64 + r)*1024 + bxt*64 + c0;
#pragma unroll
    for (int j = 0; j < 4; ++j) {
        float4 vv = ((const float4*)src)[j];
        tls[c0 + j*4 + 0][r] = f2bf(vv.x);
        tls[c0 + j*4 + 1][r] = f2bf(vv.y);
        tls[c0 + j*4 + 2][r] = f2bf(vv.z);
        tls[c0 + j*4 + 3][r] = f2bf(vv.w);
    }
    __syncthreads();
    unsigned short* dst = Wt + (size_t)(bxt*64 + r)*1024 + byt*64 + c0;
    unsigned w[8];
#pragma unroll
    for (int j = 0; j < 8; ++j)
        w[j] = (unsigned)tls[r][c0 + 2*j] | ((unsigned)tls[r][c0 + 2*j + 1] << 16);
    *(uint4*)(dst)     = make_uint4(w[0], w[1], w[2], w[3]);
    *(uint4*)(dst + 8) = make_uint4(w[4], w[5], w[6], w[7]);
}

// ---------------- rel_emb [256][16][64] f32 -> relTb [16][128][64] bf16 (buckets 0..127) ----
__global__ void relT_bf(const float* __restrict__ rel, unsigned short* __restrict__ relTb)
{
    const int t  = blockIdx.x * 256 + threadIdx.x;   // 0..16383
    const int d0 = (t & 7) * 8;
    const int n  = (t >> 3) & 127;
    const int h  = t >> 10;
    const float* src = rel + ((size_t)(n*16 + h))*64 + d0;
    float4 a = ((const float4*)src)[0], b = ((const float4*)src)[1];
    unsigned w0 = f2bf(a.x) | ((unsigned)f2bf(a.y) << 16);
    unsigned w1 = f2bf(a.z) | ((unsigned)f2bf(a.w) << 16);
    unsigned w2 = f2bf(b.x) | ((unsigned)f2bf(b.y) << 16);
    unsigned w3 = f2bf(b.z) | ((unsigned)f2bf(b.w) << 16);
    *(uint4*)(relTb + (size_t)h*8192 + n*64 + d0) = make_uint4(w0, w1, w2, w3);
}

// ---------------- bf16 MFMA GEMM: C = A[4096][1024] * Bt[1024][1024]^T ----------------
// MODE 0: fp32 row-major  MODE 1: fp32 scatter [B,H,S,D]  MODE 2: bf16 vT [B,H,D,S]
template<int MODE>
__global__ __launch_bounds__(256) void gemm_bt(const unsigned short* __restrict__ A,
                                               const unsigned short* __restrict__ Bt,
                                               float* __restrict__ C)
{
    __shared__ __align__(16) unsigned short Als[2][8192];
    __shared__ __align__(16) unsigned short Bls[2][8192];
    const int tid  = threadIdx.x;
    const int wave = tid >> 6, lane = tid & 63;
    const int wr = (wave >> 1) * 64, wc = (wave & 1) * 64;
    const int bx = blockIdx.x, by = blockIdx.y;

    const int srow = tid >> 3;
    const unsigned short* agp = A  + (size_t)(by*128)*1024 + (tid & 7)*8;
    const unsigned short* bgp = Bt + (size_t)(bx*128)*1024 + (tid & 7)*8;

    f32x4 acc[4][4];
#pragma unroll
    for (int m = 0; m < 4; ++m)
#pragma unroll
        for (int n = 0; n < 4; ++n) acc[m][n] = (f32x4)0.f;

#define STAGE(t, buf)                                                                  \
    {                                                                                  \
        const int k0s = (t) * 64;                                                      \
        _Pragma("unroll")                                                              \
        for (int j = 0; j < 4; ++j) {                                                  \
            GLOAD16(agp + (size_t)(j*32 + srow)*1024 + k0s, &Als[buf][0] + j*2048 + tid*8); \
            GLOAD16(bgp + (size_t)(j*32 + srow)*1024 + k0s, &Bls[buf][0] + j*2048 + tid*8); \
        }                                                                              \
    }

#define COMPUTE(buf)                                                                   \
    {                                                                                  \
        _Pragma("unroll")                                                              \
        for (int ks = 0; ks < 2; ++ks) {                                               \
            bf16x8 af[4], bfr[4];                                                      \
            _Pragma("unroll")                                                          \
            for (int m = 0; m < 4; ++m)                                                \
                af[m] = *(const bf16x8*)&Als[buf][(wr + m*16 + (lane & 15))*64 + ks*32 + (lane >> 4)*8]; \
            _Pragma("unroll")                                                          \
            for (int n = 0; n < 4; ++n)                                                \
                bfr[n] = *(const bf16x8*)&Bls[buf][(wc + n*16 + (lane & 15))*64 + ks*32 + (lane >> 4)*8]; \
            _Pragma("unroll")                                                          \
            for (int m = 0; m < 4; ++m)                                                \
                _Pragma("unroll")                                                      \
                for (int n = 0; n < 4; ++n)                                            \
                    acc[m][n] = __builtin_amdgcn_mfma_f32_16x16x32_bf16(af[m], bfr[n], acc[m][n], 0, 0, 0); \
        }                                                                              \
    }

    STAGE(0, 0);
    __syncthreads();
    int cur = 0;
    for (int t = 0; t < 16; ++t) {
        if (t < 15) STAGE(t + 1, cur ^ 1);
        COMPUTE(cur);
        __syncthreads();
        cur ^= 1;
    }
#undef STAGE
#undef COMPUTE

#pragma unroll
    for (int m = 0; m < 4; ++m) {
        const int r0 = by*128 + wr + m*16 + (lane >> 4)*4;
#pragma unroll
        for (int n = 0; n < 4; ++n) {
            const int col = bx*128 + wc + n*16 + (lane & 15);
            if (MODE == 2) {
                unsigned short* Cb = (unsigned short*)C;
                const int bb = r0 >> 11, ss = r0 & 2047;
                const int hh = col >> 6, dd = col & 63;
                unsigned r01 = f2bf(acc[m][n][0]) | ((unsigned)f2bf(acc[m][n][1]) << 16);
                unsigned r23 = f2bf(acc[m][n][2]) | ((unsigned)f2bf(acc[m][n][3]) << 16);
                *(uint2*)(Cb + (((size_t)bb*16 + hh)*64 + dd)*2048 + ss) = make_uint2(r01, r23);
            } else {
#pragma unroll
                for (int rg = 0; rg < 4; ++rg) {
                    const int row = r0 + rg;
                    const float val = acc[m][n][rg];
                    if (MODE == 0) {
                        C[(size_t)row*1024 + col] = val;
                    } else {
                        const int bb = row >> 11, ss = row & 2047;
                        const int hh = col >> 6,  dd = col & 63;
                        C[(((size_t)bb*16 + hh)*2048 + ss)*64 + dd] = val;
                    }
                }
            }
        }
    }
}

// ---------------- RoPE: fp32 q/k [B,H,S,D] -> bf16 qb/kb ----------------
__global__ void rope_bf16(const float* __restrict__ qf, const float* __restrict__ kf,
                          unsigned short* __restrict__ qb, unsigned short* __restrict__ kb)
{
    const int t = blockIdx.x * 256 + threadIdx.x;
    const int ten = t >> 21;
    const int r = t & ((1 << 21) - 1);
    const int dd = r & 31;
    const int s  = (r >> 5) & 2047;
    const int bh = r >> 16;
    const float* p = ten ? kf : qf;
    unsigned short* o = ten ? kb : qb;
    const size_t base = ((size_t)bh*2048 + s)*64;
    const float x0 = p[base + dd];
    const float x1 = p[base + dd + 32];
    const float f0 = (float)(dd >> 1);
    const float CC = 0.41524101186092029f;           // log2(10000)/32
    const float if0 = exp2f(-f0 * CC);
    const float if1 = exp2f(-(f0 + 16.f) * CC);
    const float a0 = (float)s * if0;
    const float a1 = (float)s * if1;
    o[base + dd]      = f2bf(x0 * cosf(a0) - x1 * sinf(a0));
    o[base + dd + 32] = f2bf(x1 * cosf(a1) + x0 * sinf(a1));
}

// ---------------- qrel via MFMA: qrelb[bh][s][n] = q[bh][s][:] . relTb[h][n][:] ----------------
// Per block: 128 q-rows x 128 buckets, K=64 (one pass). A=rel (rows=buckets), B=q (rows=s)
// so the C/D fragment's 4 consecutive rows are consecutive BUCKETS -> packed uint2 stores.
// Both fragments read contiguous bf16x8 from LDS (same pattern as verified gemm_bt).
__global__ __launch_bounds__(256) void qrel_mfma(const unsigned short* __restrict__ qb,
                                                 const unsigned short* __restrict__ relTb,
                                                 unsigned short* __restrict__ qrelb)
{
    __shared__ __align__(16) unsigned short Rls[8192];   // 128 buckets x 64
    __shared__ __align__(16) unsigned short Qls[8192];   // 128 s-rows  x 64
    const int tid  = threadIdx.x;
    const int wave = tid >> 6, lane = tid & 63;
    const int wr = (wave >> 1) * 64;     // bucket offset
    const int wc = (wave & 1) * 64;      // s offset
    const int s0 = blockIdx.x * 128;
    const int bh = blockIdx.y;
    const int h  = bh & 15;

    const unsigned short* qsrc = qb + ((size_t)bh*2048 + s0)*64;
    const unsigned short* rsrc = relTb + (size_t)h*8192;
#pragma unroll
    for (int j = 0; j < 4; ++j) {
        GLOAD16(rsrc + j*2048 + tid*8, &Rls[0] + j*2048 + tid*8);
        GLOAD16(qsrc + j*2048 + tid*8, &Qls[0] + j*2048 + tid*8);
    }

    f32x4 acc[4][4];
#pragma unroll
    for (int m = 0; m < 4; ++m)
#pragma unroll
        for (int n = 0; n < 4; ++n) acc[m][n] = (f32x4)0.f;

    __syncthreads();    // vmcnt drained + barrier: tiles visible

#pragma unroll
    for (int ks = 0; ks < 2; ++ks) {
        bf16x8 rf[4], qf[4];
#pragma unroll
        for (int m = 0; m < 4; ++m)
            rf[m] = *(const bf16x8*)&Rls[(wr + m*16 + (lane & 15))*64 + ks*32 + (lane >> 4)*8];
#pragma unroll
        for (int n = 0; n < 4; ++n)
            qf[n] = *(const bf16x8*)&Qls[(wc + n*16 + (lane & 15))*64 + ks*32 + (lane >> 4)*8];
#pragma unroll
        for (int m = 0; m < 4; ++m)
#pragma unroll
            for (int n = 0; n < 4; ++n)
                acc[m][n] = __builtin_amdgcn_mfma_f32_16x16x32_bf16(rf[m], qf[n], acc[m][n], 0, 0, 0);
    }

#pragma unroll
    for (int m = 0; m < 4; ++m) {
        const int bkt0 = wr + m*16 + (lane >> 4)*4;      // 4 consecutive buckets
#pragma unroll
        for (int n = 0; n < 4; ++n) {
            const int srow = s0 + wc + n*16 + (lane & 15);
            unsigned r01 = f2bf(acc[m][n][0]) | ((unsigned)f2bf(acc[m][n][1]) << 16);
            unsigned r23 = f2bf(acc[m][n][2]) | ((unsigned)f2bf(acc[m][n][3]) << 16);
            *(uint2*)(qrelb + ((size_t)bh*2048 + srow)*128 + bkt0) = make_uint2(r01, r23);
        }
    }
}

// ---------------- MFMA causal flash attention ----------------
// 4 waves x 16 q-rows. Swapped QK^T (S^T in regs, both operands loaded contiguous ->
// element-map-immune). P^T goes through LDS: written with the HW-pinned C/D map,
// read back as contiguous bf16x8 so PV's A (V^T) and B (P^T) share the same load
// pattern and any fragment element permutation cancels (gemm_bt-equivalent safety).
__global__ __launch_bounds__(256) void flash_mfma(
    const unsigned short* __restrict__ qb, const unsigned short* __restrict__ kb,
    const unsigned short* __restrict__ vT, const unsigned short* __restrict__ qrelb,
    unsigned short* __restrict__ ctxb)
{
    __shared__ __align__(16) unsigned short kls[2048];    // 32 keys x 64 d (swizzled chunks)
    __shared__ __align__(16) unsigned short vtls[2048];   // 64 d x 32 keys (swizzled chunks)
    __shared__ __align__(16) unsigned short Pls[2*4*16*40]; // [parity][wave][q][40]
    __shared__ __align__(16) unsigned short qrels[64*136];
    __shared__ unsigned char btbl[2048];

    const int tid = threadIdx.x;
    const int id  = blockIdx.x;
    const int bh  = id & 31;
    const int mm  = id >> 5;
    const int aa  = mm & 7, bgrp = mm >> 3;
    const int bx  = 8*bgrp + ((bgrp & 1) ? 7 - aa : aa);
    const int i0  = bx * 64;

    const int w   = tid >> 6;
    const int l   = tid & 63;
    const int q15 = l & 15;
    const int g   = l >> 4;
    const int iq  = i0 + w*16 + q15;

    // bucket table (rel 0..2047)
    for (int idx = tid; idx < 2048; idx += 256) {
        int bkt;
        if (idx < 64) bkt = idx;
        else {
            bkt = 64 + (int)(__log2f((float)idx) * 8.0f - 48.0f);
            bkt = bkt > 127 ? 127 : bkt;
        }
        btbl[idx] = (unsigned char)bkt;
    }
    // stage bias rows (bf16, pad 136)
    for (int idx = tid; idx < 1024; idx += 256) {
        const int r = idx >> 4, c8 = idx & 15;
        uint4 vv = *(const uint4*)(qrelb + ((size_t)bh*2048 + i0 + r)*128 + c8*8);
        *(uint4*)&qrels[r*136 + c8*8] = vv;
    }

    // Q fragments in registers
    bf16x8 qf0, qf1;
    {
        const unsigned short* qrow = qb + ((size_t)bh*2048 + i0 + w*16 + q15)*64;
        qf0 = *(const bf16x8*)(qrow + g*8);
        qf1 = *(const bf16x8*)(qrow + 32 + g*8);
    }

    f32x4 acc[4];   // O^T: d = dblk*16 + g*4 + reg, q = q15
#pragma unroll
    for (int d = 0; d < 4; ++d) acc[d] = (f32x4)0.f;
    float mrun = -INFINITY, lsum = 0.f;

    // staging: waves 0,1 -> K (4KB), waves 2,3 -> V^T (4KB); 2 GLOAD16/thread/tile
    const size_t headoff = (size_t)bh * 2048 * 64;
    const unsigned short* src0; const unsigned short* src1;
    unsigned short* dst0; unsigned short* dst1;
    int stepElems;
    if (w < 2) {
        const int D0 = w*2048 + l*16, D1 = D0 + 1024;
        const int r0 = D0 >> 7, c0 = (D0 >> 4) & 7;
        const int r1 = D1 >> 7, c1 = (D1 >> 4) & 7;
        src0 = kb + headoff + r0*64 + ((c0 ^ (r0 & 7)) * 8);
        src1 = kb + headoff + r1*64 + ((c1 ^ (r1 & 7)) * 8);
        dst0 = (unsigned short*)((char*)kls + D0);
        dst1 = (unsigned short*)((char*)kls + D1);
        stepElems = 2048;                       // 32 key-rows * 64
    } else {
        const int D0 = (w - 2)*2048 + l*16, D1 = D0 + 1024;
        const int r0 = D0 >> 6, c0 = (D0 >> 4) & 3;
        const int r1 = D1 >> 6, c1 = (D1 >> 4) & 3;
        src0 = vT + headoff + (size_t)r0*2048 + ((c0 ^ ((r0 >> 1) & 3)) * 8);
        src1 = vT + headoff + (size_t)r1*2048 + ((c1 ^ ((r1 >> 1) & 3)) * 8);
        dst0 = (unsigned short*)((char*)vtls + D0);
        dst1 = (unsigned short*)((char*)vtls + D1);
        stepElems = 32;                         // advance 32 keys along S
    }

    const int ntiles = (i0 >> 5) + 2;
    const float SCL = 0.1803368801111204f;      // (1/8)*log2(e)
    const int wave_imax = i0 + w*16 + 15;
    const int qrow_lds = (w*16 + q15) * 136;
    unsigned short* prow0 = &Pls[(w*16 + q15) * 40];          // parity 0
    unsigned short* prow1 = &Pls[4*16*40 + (w*16 + q15) * 40]; // parity 1

    for (int t = 0; t < ntiles; ++t) {
        const int j0 = t * 32;
        __syncthreads();                        // prev tile consumed (t=0: qrels/btbl staged)
        GLOAD16(src0 + (size_t)t*stepElems, dst0);
        GLOAD16(src1 + (size_t)t*stepElems, dst1);
        __syncthreads();                        // vmcnt drained -> tile visible

        if (j0 <= wave_imax) {
            // swapped QK^T: S^T[key][q], two 16-key subtiles
            f32x4 s0 = (f32x4)0.f, s1 = (f32x4)0.f;
#pragma unroll
            for (int ks = 0; ks < 2; ++ks) {
                const int ch = ks*4 + g;
                bf16x8 k0 = *(const bf16x8*)&kls[q15*64        + ((ch ^ (q15 & 7)) * 8)];
                bf16x8 k1 = *(const bf16x8*)&kls[(16 + q15)*64 + ((ch ^ (q15 & 7)) * 8)];
                bf16x8 qq = ks ? qf1 : qf0;
                s0 = __builtin_amdgcn_mfma_f32_16x16x32_bf16(k0, qq, s0, 0, 0, 0);
                s1 = __builtin_amdgcn_mfma_f32_16x16x32_bf16(k1, qq, s1, 0, 0, 0);
            }
            // bias + mask (key = g*4 + r (+16), pinned by verified C/D layout)
            float sv[8];
#pragma unroll
            for (int r = 0; r < 4; ++r) {
                const int rel0 = iq - (j0 + g*4 + r);
                const int rel1 = rel0 - 16;
                const int bi0 = rel0 < 0 ? 0 : rel0;
                const int bi1 = rel1 < 0 ? 0 : rel1;
                const float bias0 = bf2f(qrels[qrow_lds + btbl[bi0]]);
                const float bias1 = bf2f(qrels[qrow_lds + btbl[bi1]]);
                sv[r]     = (rel0 >= 0) ? (s0[r] + bias0) * SCL : -1e30f;
                sv[4 + r] = (rel1 >= 0) ? (s1[r] + bias1) * SCL : -1e30f;
            }
            // column (q-row) max across 8 in-lane + 4 lane-groups
            float tmax = fmaxf(fmaxf(fmaxf(sv[0], sv[1]), fmaxf(sv[2], sv[3])),
                               fmaxf(fmaxf(sv[4], sv[5]), fmaxf(sv[6], sv[7])));
            tmax = fmaxf(tmax, __shfl_xor(tmax, 16));
            tmax = fmaxf(tmax, __shfl_xor(tmax, 32));
            const float newm = fmaxf(mrun, tmax);
            const float corr = exp2f(mrun - newm);
            float p[8], ps = 0.f;
#pragma unroll
            for (int r = 0; r < 8; ++r) { p[r] = exp2f(sv[r] - newm); ps += p[r]; }
            ps += __shfl_xor(ps, 16);
            ps += __shfl_xor(ps, 32);
            lsum = lsum * corr + ps;
#pragma unroll
            for (int d = 0; d < 4; ++d) {
                acc[d][0] *= corr; acc[d][1] *= corr; acc[d][2] *= corr; acc[d][3] *= corr;
            }
            mrun = newm;

            // P^T via LDS: write with C/D map (key g*4+r at short offset),
            // read back contiguous -> fragment-element-map cancels vs V^T A-frag.
            unsigned short* pb = (t & 1) ? prow1 : prow0;
            *(unsigned*)(pb + g*4)      = f2bf(p[0]) | ((unsigned)f2bf(p[1]) << 16);
            *(unsigned*)(pb + g*4 + 2)  = f2bf(p[2]) | ((unsigned)f2bf(p[3]) << 16);
            *(unsigned*)(pb + 16 + g*4) = f2bf(p[4]) | ((unsigned)f2bf(p[5]) << 16);
            *(unsigned*)(pb + 18 + g*4) = f2bf(p[6]) | ((unsigned)f2bf(p[7]) << 16);
            asm volatile("s_waitcnt lgkmcnt(0)" ::: "memory");   // intra-wave write->read fence
            __builtin_amdgcn_sched_barrier(0);                   // rule 18: pin the fence
            bf16x8 pfrag = *(const bf16x8*)(pb + g*8);           // keys g*8..g*8+7, col q15

            // PV: O^T += V^T * P^T
#pragma unroll
            for (int dblk = 0; dblk < 4; ++dblk) {
                const int d = dblk*16 + q15;
                bf16x8 vf = *(const bf16x8*)&vtls[d*32 + ((g ^ ((d >> 1) & 3)) * 8)];
                acc[dblk] = __builtin_amdgcn_mfma_f32_16x16x32_bf16(vf, pfrag, acc[dblk], 0, 0, 0);
            }
        }
    }

    const float inv = 1.0f / lsum;
    const int s  = i0 + w*16 + q15;
    const int b2 = bh >> 4, hh = bh & 15;
    unsigned short* obase = ctxb + (((size_t)b2*2048 + s)*16 + hh)*64;
#pragma unroll
    for (int dblk = 0; dblk < 4; ++dblk) {
        const int d0 = dblk*16 + g*4;
        unsigned r01 = f2bf(acc[dblk][0]*inv) | ((unsigned)f2bf(acc[dblk][1]*inv) << 16);
        unsigned r23 = f2bf(acc[dblk][2]*inv) | ((unsigned)f2bf(acc[dblk][3]*inv) << 16);
        *(uint2*)(obase + d0) = make_uint2(r01, r23);
    }
}

extern "C" void kernel_launch(void* const* d_in, const int* in_sizes, int n_in,
                              void* d_out, int out_size, void* d_ws, size_t ws_size,
                              hipStream_t stream)
{
    const float* x   = (const float*)d_in[0];
    const float* Wq  = (const float*)d_in[1];
    const float* Wk  = (const float*)d_in[2];
    const float* Wv  = (const float*)d_in[3];
    const float* Wo  = (const float*)d_in[4];
    const float* rel = (const float*)d_in[5];

    float* ws = (float*)d_ws;
    // Layout (float offsets). qrelb = 8,388,608 bf16 = 4,194,304 floats (32 heads full).
    float* qf32 = ws;                                           // 0 .. 4194304 (dead after rope)
    float* kf32 = ws + 4194304;                                 // .. 8388608   (dead after rope)
    unsigned short* qb    = (unsigned short*)(ws + 8388608);    // 4,194,304 bf16 (2M floats)
    unsigned short* kbb   = (unsigned short*)(ws + 10485760);   // 4,194,304 bf16
    unsigned short* qrelb = (unsigned short*)(ws + 12582912);   // 8,388,608 bf16 (4M floats)
    unsigned short* vTb   = (unsigned short*)(ws + 16777216);   // 4,194,304 bf16
    unsigned short* xb    = (unsigned short*)(ws + 18874368);   // 4,194,304 bf16 (transient)
    unsigned short* wtq   = (unsigned short*)(ws + 20971520);   // 1,048,576 bf16 each
    unsigned short* wtk   = (unsigned short*)(ws + 21495808);
    unsigned short* wtv   = (unsigned short*)(ws + 22020096);
    unsigned short* wto   = (unsigned short*)(ws + 22544384);
    unsigned short* relTb = (unsigned short*)(ws + 23068672);   // 131,072 bf16; ends 23134208 OK
    unsigned short* ctxb  = (unsigned short*)ws;                // over qf32 (dead by then)

    tobf16<<<2048, 256, 0, stream>>>(x, xb);
    transp_bf<<<256, 256, 0, stream>>>(Wq, wtq);
    transp_bf<<<256, 256, 0, stream>>>(Wk, wtk);
    transp_bf<<<256, 256, 0, stream>>>(Wv, wtv);
    transp_bf<<<256, 256, 0, stream>>>(Wo, wto);
    relT_bf<<<64, 256, 0, stream>>>(rel, relTb);

    dim3 gemm_grid(8, 32);
    gemm_bt<1><<<gemm_grid, 256, 0, stream>>>(xb, wtq, qf32);
    gemm_bt<1><<<gemm_grid, 256, 0, stream>>>(xb, wtk, kf32);
    gemm_bt<2><<<gemm_grid, 256, 0, stream>>>(xb, wtv, (float*)vTb);
    rope_bf16<<<16384, 256, 0, stream>>>(qf32, kf32, qb, kbb);
    qrel_mfma<<<dim3(16, 32), 256, 0, stream>>>(qb, relTb, qrelb);
    flash_mfma<<<1024, 256, 0, stream>>>(qb, kbb, vTb, qrelb, ctxb);
    gemm_bt<0><<<gemm_grid, 256, 0, stream>>>(ctxb, wto, (float*)d_out);
}

// Round 11
// 208.875 us; speedup vs baseline: 43.5638x; 1.1857x over previous
//
#include <hip/hip_runtime.h>
#include <hip/hip_bf16.h>
#include <math.h>

// Problem constants: B=2, S=2048, E=1024, H=16, D=64, buckets 0..127 (causal => rel>=0)

typedef __attribute__((ext_vector_type(8))) short bf16x8;
typedef __attribute__((ext_vector_type(4))) float f32x4;

static __device__ __forceinline__ unsigned short f2bf(float x) {
    unsigned u = __float_as_uint(x);
    unsigned r = (u + 0x7fffu + ((u >> 16) & 1u)) >> 16;   // RNE
    return (unsigned short)r;
}
static __device__ __forceinline__ float bf2f(unsigned short h) {
    return __uint_as_float(((unsigned)h) << 16);
}

// async 16B global->LDS (HW uses wave-uniform LDS base + lane*16 -> dest must be linear)
#define GLOAD16(gp, lp)                                                            \
    __builtin_amdgcn_global_load_lds(                                              \
        (const __attribute__((address_space(1))) unsigned int*)(gp),               \
        (__attribute__((address_space(3))) unsigned int*)(lp), 16, 0, 0)

// ---------------- f32 -> bf16 convert ----------------
__global__ void tobf16(const float* __restrict__ in, unsigned short* __restrict__ out)
{
    const size_t t = (size_t)blockIdx.x * 256 + threadIdx.x;
    const float4* p = (const float4*)(in + t*8);
    float4 a = p[0], b = p[1];
    unsigned w0 = f2bf(a.x) | ((unsigned)f2bf(a.y) << 16);
    unsigned w1 = f2bf(a.z) | ((unsigned)f2bf(a.w) << 16);
    unsigned w2 = f2bf(b.x) | ((unsigned)f2bf(b.y) << 16);
    unsigned w3 = f2bf(b.z) | ((unsigned)f2bf(b.w) << 16);
    *(uint4*)(out + t*8) = make_uint4(w0, w1, w2, w3);
}

// ---------------- 4x W [K][N] f32 -> Wt [N][K] bf16, fused by blockIdx.y ----------------
__global__ void transp4(const float* __restrict__ W0, const float* __restrict__ W1,
                        const float* __restrict__ W2, const float* __restrict__ W3,
                        unsigned short* __restrict__ T0, unsigned short* __restrict__ T1,
                        unsigned short* __restrict__ T2, unsigned short* __restrict__ T3)
{
    const int z = blockIdx.y;
    const float* W = (z == 0) ? W0 : (z == 1) ? W1 : (z == 2) ? W2 : W3;
    unsigned short* Wt = (z == 0) ? T0 : (z == 1) ? T1 : (z == 2) ? T2 : T3;

    __shared__ unsigned short tls[64][65];
    const int tid = threadIdx.x;
    const int bxt = blockIdx.x & 15;
    const int byt = blockIdx.x >> 4;
    const int r   = tid >> 2;
    const int c0  = (tid & 3) * 16;
    const float* src = W + (size_t)(byt*64 + r)*1024 + bxt*64 + c0;
#pragma unroll
    for (int j = 0; j < 4; ++j) {
        float4 vv = ((const float4*)src)[j];
        tls[c0 + j*4 + 0][r] = f2bf(vv.x);
        tls[c0 + j*4 + 1][r] = f2bf(vv.y);
        tls[c0 + j*4 + 2][r] = f2bf(vv.z);
        tls[c0 + j*4 + 3][r] = f2bf(vv.w);
    }
    __syncthreads();
    unsigned short* dst = Wt + (size_t)(bxt*64 + r)*1024 + byt*64 + c0;
    unsigned w[8];
#pragma unroll
    for (int j = 0; j < 8; ++j)
        w[j] = (unsigned)tls[r][c0 + 2*j] | ((unsigned)tls[r][c0 + 2*j + 1] << 16);
    *(uint4*)(dst)     = make_uint4(w[0], w[1], w[2], w[3]);
    *(uint4*)(dst + 8) = make_uint4(w[4], w[5], w[6], w[7]);
}

// ---------------- rel_emb [256][16][64] f32 -> relTb [16][128][64] bf16 ----------------
__global__ void relT_bf(const float* __restrict__ rel, unsigned short* __restrict__ relTb)
{
    const int t  = blockIdx.x * 256 + threadIdx.x;   // 0..16383
    const int d0 = (t & 7) * 8;
    const int n  = (t >> 3) & 127;
    const int h  = t >> 10;
    const float* src = rel + ((size_t)(n*16 + h))*64 + d0;
    float4 a = ((const float4*)src)[0], b = ((const float4*)src)[1];
    unsigned w0 = f2bf(a.x) | ((unsigned)f2bf(a.y) << 16);
    unsigned w1 = f2bf(a.z) | ((unsigned)f2bf(a.w) << 16);
    unsigned w2 = f2bf(b.x) | ((unsigned)f2bf(b.y) << 16);
    unsigned w3 = f2bf(b.z) | ((unsigned)f2bf(b.w) << 16);
    *(uint4*)(relTb + (size_t)h*8192 + n*64 + d0) = make_uint4(w0, w1, w2, w3);
}

// ---------------- shared GEMM body macros (128x128 tile, BK=64, dbuf, gload_lds) ----------
#define GEMM_STAGE(t, buf)                                                             \
    {                                                                                  \
        const int k0s = (t) * 64;                                                      \
        _Pragma("unroll")                                                              \
        for (int j = 0; j < 4; ++j) {                                                  \
            GLOAD16(agp + (size_t)(j*32 + srow)*1024 + k0s, &Als[buf][0] + j*2048 + tid*8); \
            GLOAD16(bgp + (size_t)(j*32 + srow)*1024 + k0s, &Bls[buf][0] + j*2048 + tid*8); \
        }                                                                              \
    }

#define GEMM_COMPUTE(buf)                                                              \
    {                                                                                  \
        _Pragma("unroll")                                                              \
        for (int ks = 0; ks < 2; ++ks) {                                               \
            bf16x8 af[4], bfr[4];                                                      \
            _Pragma("unroll")                                                          \
            for (int m = 0; m < 4; ++m)                                                \
                af[m] = *(const bf16x8*)&Als[buf][(wr + m*16 + (lane & 15))*64 + ks*32 + (lane >> 4)*8]; \
            _Pragma("unroll")                                                          \
            for (int n = 0; n < 4; ++n)                                                \
                bfr[n] = *(const bf16x8*)&Bls[buf][(wc + n*16 + (lane & 15))*64 + ks*32 + (lane >> 4)*8]; \
            _Pragma("unroll")                                                          \
            for (int m = 0; m < 4; ++m)                                                \
                _Pragma("unroll")                                                      \
                for (int n = 0; n < 4; ++n)                                            \
                    acc[m][n] = __builtin_amdgcn_mfma_f32_16x16x32_bf16(af[m], bfr[n], acc[m][n], 0, 0, 0); \
        }                                                                              \
    }

// ---------------- fused QKV GEMM: z=0 -> q fp32 [B,H,S,D]; z=1 -> k fp32; z=2 -> vT bf16 ----
__global__ __launch_bounds__(256) void gemm_qkv(const unsigned short* __restrict__ A,
    const unsigned short* __restrict__ wtq, const unsigned short* __restrict__ wtk,
    const unsigned short* __restrict__ wtv,
    float* __restrict__ qf, float* __restrict__ kf, unsigned short* __restrict__ vTb)
{
    __shared__ __align__(16) unsigned short Als[2][8192];
    __shared__ __align__(16) unsigned short Bls[2][8192];
    const int z = blockIdx.z;
    const unsigned short* Bt = (z == 0) ? wtq : (z == 1) ? wtk : wtv;

    const int tid  = threadIdx.x;
    const int wave = tid >> 6, lane = tid & 63;
    const int wr = (wave >> 1) * 64, wc = (wave & 1) * 64;
    const int bx = blockIdx.x, by = blockIdx.y;
    const int srow = tid >> 3;
    const unsigned short* agp = A  + (size_t)(by*128)*1024 + (tid & 7)*8;
    const unsigned short* bgp = Bt + (size_t)(bx*128)*1024 + (tid & 7)*8;

    f32x4 acc[4][4];
#pragma unroll
    for (int m = 0; m < 4; ++m)
#pragma unroll
        for (int n = 0; n < 4; ++n) acc[m][n] = (f32x4)0.f;

    GEMM_STAGE(0, 0);
    __syncthreads();
    int cur = 0;
    for (int t = 0; t < 16; ++t) {
        if (t < 15) GEMM_STAGE(t + 1, cur ^ 1);
        GEMM_COMPUTE(cur);
        __syncthreads();
        cur ^= 1;
    }

#pragma unroll
    for (int m = 0; m < 4; ++m) {
        const int r0 = by*128 + wr + m*16 + (lane >> 4)*4;
#pragma unroll
        for (int n = 0; n < 4; ++n) {
            const int col = bx*128 + wc + n*16 + (lane & 15);
            if (z == 2) {
                const int bb = r0 >> 11, ss = r0 & 2047;
                const int hh = col >> 6, dd = col & 63;
                unsigned r01 = f2bf(acc[m][n][0]) | ((unsigned)f2bf(acc[m][n][1]) << 16);
                unsigned r23 = f2bf(acc[m][n][2]) | ((unsigned)f2bf(acc[m][n][3]) << 16);
                *(uint2*)(vTb + (((size_t)bb*16 + hh)*64 + dd)*2048 + ss) = make_uint2(r01, r23);
            } else {
                float* C = z ? kf : qf;
#pragma unroll
                for (int rg = 0; rg < 4; ++rg) {
                    const int row = r0 + rg;
                    const int bb = row >> 11, ss = row & 2047;
                    const int hh = col >> 6,  dd = col & 63;
                    C[(((size_t)bb*16 + hh)*2048 + ss)*64 + dd] = acc[m][n][rg];
                }
            }
        }
    }
}

// ---------------- Wo GEMM: C fp32 row-major ----------------
__global__ __launch_bounds__(256) void gemm_o(const unsigned short* __restrict__ A,
                                              const unsigned short* __restrict__ Bt,
                                              float* __restrict__ C)
{
    __shared__ __align__(16) unsigned short Als[2][8192];
    __shared__ __align__(16) unsigned short Bls[2][8192];
    const int tid  = threadIdx.x;
    const int wave = tid >> 6, lane = tid & 63;
    const int wr = (wave >> 1) * 64, wc = (wave & 1) * 64;
    const int bx = blockIdx.x, by = blockIdx.y;
    const int srow = tid >> 3;
    const unsigned short* agp = A  + (size_t)(by*128)*1024 + (tid & 7)*8;
    const unsigned short* bgp = Bt + (size_t)(bx*128)*1024 + (tid & 7)*8;

    f32x4 acc[4][4];
#pragma unroll
    for (int m = 0; m < 4; ++m)
#pragma unroll
        for (int n = 0; n < 4; ++n) acc[m][n] = (f32x4)0.f;

    GEMM_STAGE(0, 0);
    __syncthreads();
    int cur = 0;
    for (int t = 0; t < 16; ++t) {
        if (t < 15) GEMM_STAGE(t + 1, cur ^ 1);
        GEMM_COMPUTE(cur);
        __syncthreads();
        cur ^= 1;
    }

#pragma unroll
    for (int m = 0; m < 4; ++m) {
        const int r0 = by*128 + wr + m*16 + (lane >> 4)*4;
#pragma unroll
        for (int n = 0; n < 4; ++n) {
            const int col = bx*128 + wc + n*16 + (lane & 15);
#pragma unroll
            for (int rg = 0; rg < 4; ++rg)
                C[(size_t)(r0 + rg)*1024 + col] = acc[m][n][rg];
        }
    }
}

// ---------------- RoPE: fp32 q/k [B,H,S,D] -> bf16 qb/kb ----------------
__global__ void rope_bf16(const float* __restrict__ qf, const float* __restrict__ kf,
                          unsigned short* __restrict__ qb, unsigned short* __restrict__ kb)
{
    const int t = blockIdx.x * 256 + threadIdx.x;
    const int ten = t >> 21;
    const int r = t & ((1 << 21) - 1);
    const int dd = r & 31;
    const int s  = (r >> 5) & 2047;
    const int bh = r >> 16;
    const float* p = ten ? kf : qf;
    unsigned short* o = ten ? kb : qb;
    const size_t base = ((size_t)bh*2048 + s)*64;
    const float x0 = p[base + dd];
    const float x1 = p[base + dd + 32];
    const float f0 = (float)(dd >> 1);
    const float CC = 0.41524101186092029f;           // log2(10000)/32
    const float if0 = exp2f(-f0 * CC);
    const float if1 = exp2f(-(f0 + 16.f) * CC);
    const float a0 = (float)s * if0;
    const float a1 = (float)s * if1;
    o[base + dd]      = f2bf(x0 * cosf(a0) - x1 * sinf(a0));
    o[base + dd + 32] = f2bf(x1 * cosf(a1) + x0 * sinf(a1));
}

// ---------------- qrel via MFMA (verified r10) ----------------
__global__ __launch_bounds__(256) void qrel_mfma(const unsigned short* __restrict__ qb,
                                                 const unsigned short* __restrict__ relTb,
                                                 unsigned short* __restrict__ qrelb)
{
    __shared__ __align__(16) unsigned short Rls[8192];   // 128 buckets x 64
    __shared__ __align__(16) unsigned short Qls[8192];   // 128 s-rows  x 64
    const int tid  = threadIdx.x;
    const int wave = tid >> 6, lane = tid & 63;
    const int wr = (wave >> 1) * 64;     // bucket offset
    const int wc = (wave & 1) * 64;      // s offset
    const int s0 = blockIdx.x * 128;
    const int bh = blockIdx.y;
    const int h  = bh & 15;

    const unsigned short* qsrc = qb + ((size_t)bh*2048 + s0)*64;
    const unsigned short* rsrc = relTb + (size_t)h*8192;
#pragma unroll
    for (int j = 0; j < 4; ++j) {
        GLOAD16(rsrc + j*2048 + tid*8, &Rls[0] + j*2048 + tid*8);
        GLOAD16(qsrc + j*2048 + tid*8, &Qls[0] + j*2048 + tid*8);
    }

    f32x4 acc[4][4];
#pragma unroll
    for (int m = 0; m < 4; ++m)
#pragma unroll
        for (int n = 0; n < 4; ++n) acc[m][n] = (f32x4)0.f;

    __syncthreads();

#pragma unroll
    for (int ks = 0; ks < 2; ++ks) {
        bf16x8 rf[4], qf[4];
#pragma unroll
        for (int m = 0; m < 4; ++m)
            rf[m] = *(const bf16x8*)&Rls[(wr + m*16 + (lane & 15))*64 + ks*32 + (lane >> 4)*8];
#pragma unroll
        for (int n = 0; n < 4; ++n)
            qf[n] = *(const bf16x8*)&Qls[(wc + n*16 + (lane & 15))*64 + ks*32 + (lane >> 4)*8];
#pragma unroll
        for (int m = 0; m < 4; ++m)
#pragma unroll
            for (int n = 0; n < 4; ++n)
                acc[m][n] = __builtin_amdgcn_mfma_f32_16x16x32_bf16(rf[m], qf[n], acc[m][n], 0, 0, 0);
    }

#pragma unroll
    for (int m = 0; m < 4; ++m) {
        const int bkt0 = wr + m*16 + (lane >> 4)*4;
#pragma unroll
        for (int n = 0; n < 4; ++n) {
            const int srow = s0 + wc + n*16 + (lane & 15);
            unsigned r01 = f2bf(acc[m][n][0]) | ((unsigned)f2bf(acc[m][n][1]) << 16);
            unsigned r23 = f2bf(acc[m][n][2]) | ((unsigned)f2bf(acc[m][n][3]) << 16);
            *(uint2*)(qrelb + ((size_t)bh*2048 + srow)*128 + bkt0) = make_uint2(r01, r23);
        }
    }
}

// ---------------- MFMA causal flash attention, 64-key tiles ----------------
// 4 waves x 16 q-rows. Swapped QK^T (S^T in regs). P^T built in-register via the
// 8-shuffle network (r7 construction — proven equivalent to the LDS path by r7/r8
// bit-identity). Defer-max (THR=8, base-2). K and V^T share the c^=(r&7) granule
// swizzle (both rows are 128 B), staged via pre-swizzled global_load_lds sources.
__global__ __launch_bounds__(256) void flash_mfma(
    const unsigned short* __restrict__ qb, const unsigned short* __restrict__ kb,
    const unsigned short* __restrict__ vT, const unsigned short* __restrict__ qrelb,
    unsigned short* __restrict__ ctxb)
{
    __shared__ __align__(16) unsigned short kls[4096];    // 64 keys x 64 d (swizzled granules)
    __shared__ __align__(16) unsigned short vtls[4096];   // 64 d x 64 keys (swizzled granules)
    __shared__ __align__(16) unsigned short qrels[64*136];
    __shared__ unsigned char btbl[2048];

    const int tid = threadIdx.x;
    const int id  = blockIdx.x;
    const int bh  = id & 31;
    const int mm  = id >> 5;
    const int aa  = mm & 7, bgrp = mm >> 3;
    const int bx  = 8*bgrp + ((bgrp & 1) ? 7 - aa : aa);
    const int i0  = bx * 64;

    const int w   = tid >> 6;
    const int l   = tid & 63;
    const int q15 = l & 15;
    const int g   = l >> 4;
    const int iq  = i0 + w*16 + q15;

    for (int idx = tid; idx < 2048; idx += 256) {
        int bkt;
        if (idx < 64) bkt = idx;
        else {
            bkt = 64 + (int)(__log2f((float)idx) * 8.0f - 48.0f);
            bkt = bkt > 127 ? 127 : bkt;
        }
        btbl[idx] = (unsigned char)bkt;
    }
    for (int idx = tid; idx < 1024; idx += 256) {
        const int r = idx >> 4, c8 = idx & 15;
        uint4 vv = *(const uint4*)(qrelb + ((size_t)bh*2048 + i0 + r)*128 + c8*8);
        *(uint4*)&qrels[r*136 + c8*8] = vv;
    }

    bf16x8 qf0, qf1;
    {
        const unsigned short* qrow = qb + ((size_t)bh*2048 + i0 + w*16 + q15)*64;
        qf0 = *(const bf16x8*)(qrow + g*8);
        qf1 = *(const bf16x8*)(qrow + 32 + g*8);
    }

    f32x4 acc[4];
#pragma unroll
    for (int d = 0; d < 4; ++d) acc[d] = (f32x4)0.f;
    float mrun = -INFINITY, lsum = 0.f;

    // staging: waves 0,1 -> K (8KB), waves 2,3 -> V^T (8KB); 4 GLOAD16/thread/tile.
    // r,c static per (thread,i); only j0 moves the global base.
    const size_t headoff = (size_t)bh * 2048 * 64;
    const unsigned short* gbase;
    int jstride;
    char* lbase;
    if (tid < 128) { gbase = kb + headoff; jstride = 64; lbase = (char*)kls; }
    else           { gbase = vT + headoff; jstride = 1;  lbase = (char*)vtls; }
    int soff[4]; char* ldst[4];
#pragma unroll
    for (int i = 0; i < 4; ++i) {
        const int D = (tid & 127)*16 + i*2048;
        const int r = D >> 7, c = (D >> 4) & 7;
        soff[i] = (tid < 128) ? (r*64 + ((c ^ (r & 7))*8))
                              : (r*2048 + ((c ^ (r & 7))*8));
        ldst[i] = lbase + D;
    }

    const int ntiles = bx + 1;
    const float SCL = 0.1803368801111204f;      // (1/8)*log2(e)
    const int qrow_lds = (w*16 + q15) * 136;
    const int srcA = ((2*g) & 3)*16 + q15;
    const int srcB = ((2*g + 1) & 3)*16 + q15;

    for (int t = 0; t < ntiles; ++t) {
        const int j0 = t * 64;
        __syncthreads();                        // prev tile consumed (t=0: qrels/btbl staged)
        {
            const unsigned short* gt = gbase + (size_t)j0 * jstride;
#pragma unroll
            for (int i = 0; i < 4; ++i) GLOAD16(gt + soff[i], ldst[i]);
        }
        __syncthreads();                        // vmcnt drained -> tile visible

        // swapped QK^T: 4 key-subtiles of 16
        f32x4 s[4];
#pragma unroll
        for (int ss = 0; ss < 4; ++ss) s[ss] = (f32x4)0.f;
#pragma unroll
        for (int ks = 0; ks < 2; ++ks) {
            const bf16x8 qq = ks ? qf1 : qf0;
            const int gr = ((ks*4 + g) ^ (q15 & 7)) * 8;
#pragma unroll
            for (int ss = 0; ss < 4; ++ss) {
                bf16x8 kf = *(const bf16x8*)&kls[(ss*16 + q15)*64 + gr];
                s[ss] = __builtin_amdgcn_mfma_f32_16x16x32_bf16(kf, qq, s[ss], 0, 0, 0);
            }
        }
        // bias + mask (key = j0 + ss*16 + g*4 + r)
        float sv[16];
        float tmax = -INFINITY;
#pragma unroll
        for (int ss = 0; ss < 4; ++ss) {
#pragma unroll
            for (int r = 0; r < 4; ++r) {
                const int rel = iq - (j0 + ss*16 + g*4 + r);
                const int bi = rel < 0 ? 0 : rel;
                const float bias = bf2f(qrels[qrow_lds + btbl[bi]]);
                const float val = (s[ss][r] + bias) * SCL;
                sv[ss*4 + r] = (rel >= 0) ? val : -1e30f;
                tmax = fmaxf(tmax, sv[ss*4 + r]);
            }
        }
        tmax = fmaxf(tmax, __shfl_xor(tmax, 16));
        tmax = fmaxf(tmax, __shfl_xor(tmax, 32));

        // defer-max: skip rescale when all columns grew <= 8 (p then bounded by 2^8)
        float newm = mrun;
        if (!__all(tmax - mrun <= 8.0f)) {
            newm = fmaxf(mrun, tmax);
            const float corr = exp2f(mrun - newm);
            lsum *= corr;
#pragma unroll
            for (int d = 0; d < 4; ++d) {
                acc[d][0] *= corr; acc[d][1] *= corr; acc[d][2] *= corr; acc[d][3] *= corr;
            }
            mrun = newm;
        }

        float p[16], ps = 0.f;
#pragma unroll
        for (int j = 0; j < 16; ++j) { p[j] = exp2f(sv[j] - newm); ps += p[j]; }
        ps += __shfl_xor(ps, 16);
        ps += __shfl_xor(ps, 32);
        lsum += ps;

        // two 32-key chunks: build P^T B-frag via shuffles, then PV
#pragma unroll
        for (int ck = 0; ck < 2; ++ck) {
            unsigned w00 = f2bf(p[8*ck+0]) | ((unsigned)f2bf(p[8*ck+1]) << 16);
            unsigned w01 = f2bf(p[8*ck+2]) | ((unsigned)f2bf(p[8*ck+3]) << 16);
            unsigned w10 = f2bf(p[8*ck+4]) | ((unsigned)f2bf(p[8*ck+5]) << 16);
            unsigned w11 = f2bf(p[8*ck+6]) | ((unsigned)f2bf(p[8*ck+7]) << 16);
            unsigned a0 = (unsigned)__shfl((int)w00, srcA);
            unsigned b0 = (unsigned)__shfl((int)w10, srcA);
            unsigned a1 = (unsigned)__shfl((int)w01, srcA);
            unsigned b1 = (unsigned)__shfl((int)w11, srcA);
            unsigned a2 = (unsigned)__shfl((int)w00, srcB);
            unsigned b2 = (unsigned)__shfl((int)w10, srcB);
            unsigned a3 = (unsigned)__shfl((int)w01, srcB);
            unsigned b3 = (unsigned)__shfl((int)w11, srcB);
            union { unsigned u[4]; bf16x8 v; } pu;
            pu.u[0] = (g < 2) ? a0 : b0;
            pu.u[1] = (g < 2) ? a1 : b1;
            pu.u[2] = (g < 2) ? a2 : b2;
            pu.u[3] = (g < 2) ? a3 : b3;
#pragma unroll
            for (int dblk = 0; dblk < 4; ++dblk) {
                const int d2 = dblk*16 + q15;
                bf16x8 vf = *(const bf16x8*)&vtls[d2*64 + (((ck*4 + g) ^ (d2 & 7))*8)];
                acc[dblk] = __builtin_amdgcn_mfma_f32_16x16x32_bf16(vf, pu.v, acc[dblk], 0, 0, 0);
            }
        }
    }

    const float inv = 1.0f / lsum;
    const int s2 = i0 + w*16 + q15;
    const int b2 = bh >> 4, hh = bh & 15;
    unsigned short* obase = ctxb + (((size_t)b2*2048 + s2)*16 + hh)*64;
#pragma unroll
    for (int dblk = 0; dblk < 4; ++dblk) {
        const int d0 = dblk*16 + g*4;
        unsigned r01 = f2bf(acc[dblk][0]*inv) | ((unsigned)f2bf(acc[dblk][1]*inv) << 16);
        unsigned r23 = f2bf(acc[dblk][2]*inv) | ((unsigned)f2bf(acc[dblk][3]*inv) << 16);
        *(uint2*)(obase + d0) = make_uint2(r01, r23);
    }
}

extern "C" void kernel_launch(void* const* d_in, const int* in_sizes, int n_in,
                              void* d_out, int out_size, void* d_ws, size_t ws_size,
                              hipStream_t stream)
{
    const float* x   = (const float*)d_in[0];
    const float* Wq  = (const float*)d_in[1];
    const float* Wk  = (const float*)d_in[2];
    const float* Wv  = (const float*)d_in[3];
    const float* Wo  = (const float*)d_in[4];
    const float* rel = (const float*)d_in[5];

    float* ws = (float*)d_ws;
    float* qf32 = ws;                                           // dead after rope
    float* kf32 = ws + 4194304;                                 // dead after rope
    unsigned short* qb    = (unsigned short*)(ws + 8388608);    // 4,194,304 bf16
    unsigned short* kbb   = (unsigned short*)(ws + 10485760);   // 4,194,304 bf16
    unsigned short* qrelb = (unsigned short*)(ws + 12582912);   // 8,388,608 bf16 (4M floats)
    unsigned short* vTb   = (unsigned short*)(ws + 16777216);   // 4,194,304 bf16
    unsigned short* xb    = (unsigned short*)(ws + 18874368);   // 4,194,304 bf16
    unsigned short* wtq   = (unsigned short*)(ws + 20971520);   // 1,048,576 bf16 each
    unsigned short* wtk   = (unsigned short*)(ws + 21495808);
    unsigned short* wtv   = (unsigned short*)(ws + 22020096);
    unsigned short* wto   = (unsigned short*)(ws + 22544384);
    unsigned short* relTb = (unsigned short*)(ws + 23068672);   // 131,072 bf16
    unsigned short* ctxb  = (unsigned short*)ws;                // over qf32 (dead by then)

    tobf16<<<2048, 256, 0, stream>>>(x, xb);
    transp4<<<dim3(256, 4), 256, 0, stream>>>(Wq, Wk, Wv, Wo, wtq, wtk, wtv, wto);
    relT_bf<<<64, 256, 0, stream>>>(rel, relTb);

    gemm_qkv<<<dim3(8, 32, 3), 256, 0, stream>>>(xb, wtq, wtk, wtv, qf32, kf32, vTb);
    rope_bf16<<<16384, 256, 0, stream>>>(qf32, kf32, qb, kbb);
    qrel_mfma<<<dim3(16, 32), 256, 0, stream>>>(qb, relTb, qrelb);
    flash_mfma<<<1024, 256, 0, stream>>>(qb, kbb, vTb, qrelb, ctxb);
    gemm_o<<<dim3(8, 32), 256, 0, stream>>>(ctxb, wto, (float*)d_out);
}

// Round 12
// 205.008 us; speedup vs baseline: 44.3856x; 1.0189x over previous
//
#include <hip/hip_runtime.h>
#include <hip/hip_bf16.h>
#include <math.h>

// Problem constants: B=2, S=2048, E=1024, H=16, D=64, buckets 0..127 (causal => rel>=0)

typedef __attribute__((ext_vector_type(8))) short bf16x8;
typedef __attribute__((ext_vector_type(4))) float f32x4;

static __device__ __forceinline__ unsigned short f2bf(float x) {
    unsigned u = __float_as_uint(x);
    unsigned r = (u + 0x7fffu + ((u >> 16) & 1u)) >> 16;   // RNE
    return (unsigned short)r;
}
static __device__ __forceinline__ float bf2f(unsigned short h) {
    return __uint_as_float(((unsigned)h) << 16);
}
static __device__ __forceinline__ unsigned cvtpk(float lo, float hi) {
    unsigned r;
    asm("v_cvt_pk_bf16_f32 %0, %1, %2" : "=v"(r) : "v"(lo), "v"(hi));
    return r;   // D[15:0]=bf16(lo), D[31:16]=bf16(hi)
}
static __device__ __forceinline__ float fexp2(float x) {
    return __builtin_amdgcn_exp2f(x);
}

// async 16B global->LDS (HW uses wave-uniform LDS base + lane*16 -> dest must be linear)
#define GLOAD16(gp, lp)                                                            \
    __builtin_amdgcn_global_load_lds(                                              \
        (const __attribute__((address_space(1))) unsigned int*)(gp),               \
        (__attribute__((address_space(3))) unsigned int*)(lp), 16, 0, 0)

// ---------------- fused prep: x->bf16 | 4x W transpose->bf16 | relT ----------------
__global__ void prep(const float* __restrict__ x,
                     const float* __restrict__ W0, const float* __restrict__ W1,
                     const float* __restrict__ W2, const float* __restrict__ W3,
                     const float* __restrict__ rel,
                     unsigned short* __restrict__ xb,
                     unsigned short* __restrict__ T0, unsigned short* __restrict__ T1,
                     unsigned short* __restrict__ T2, unsigned short* __restrict__ T3,
                     unsigned short* __restrict__ relTb)
{
    __shared__ unsigned short tls[64][65];
    const int id  = blockIdx.x;
    const int tid = threadIdx.x;
    if (id < 2048) {                         // tobf16: x -> xb
        const size_t t = (size_t)id * 256 + tid;
        const float4* p = (const float4*)(x + t*8);
        float4 a = p[0], b = p[1];
        unsigned w0 = cvtpk(a.x, a.y), w1 = cvtpk(a.z, a.w);
        unsigned w2 = cvtpk(b.x, b.y), w3 = cvtpk(b.z, b.w);
        *(uint4*)(xb + t*8) = make_uint4(w0, w1, w2, w3);
    } else if (id < 3072) {                  // transp4
        const int local = id - 2048;
        const int z  = local >> 8;
        const float* W = (z == 0) ? W0 : (z == 1) ? W1 : (z == 2) ? W2 : W3;
        unsigned short* Wt = (z == 0) ? T0 : (z == 1) ? T1 : (z == 2) ? T2 : T3;
        const int bb  = local & 255;
        const int bxt = bb & 15;
        const int byt = bb >> 4;
        const int r   = tid >> 2;
        const int c0  = (tid & 3) * 16;
        const float* src = W + (size_t)(byt*64 + r)*1024 + bxt*64 + c0;
#pragma unroll
        for (int j = 0; j < 4; ++j) {
            float4 vv = ((const float4*)src)[j];
            tls[c0 + j*4 + 0][r] = f2bf(vv.x);
            tls[c0 + j*4 + 1][r] = f2bf(vv.y);
            tls[c0 + j*4 + 2][r] = f2bf(vv.z);
            tls[c0 + j*4 + 3][r] = f2bf(vv.w);
        }
        __syncthreads();
        unsigned short* dst = Wt + (size_t)(bxt*64 + r)*1024 + byt*64 + c0;
        unsigned w[8];
#pragma unroll
        for (int j = 0; j < 8; ++j)
            w[j] = (unsigned)tls[r][c0 + 2*j] | ((unsigned)tls[r][c0 + 2*j + 1] << 16);
        *(uint4*)(dst)     = make_uint4(w[0], w[1], w[2], w[3]);
        *(uint4*)(dst + 8) = make_uint4(w[4], w[5], w[6], w[7]);
    } else {                                 // relT: rel_emb -> [16][128][64] bf16
        const int t  = (id - 3072) * 256 + tid;
        const int d0 = (t & 7) * 8;
        const int n  = (t >> 3) & 127;
        const int h  = t >> 10;
        const float* src = rel + ((size_t)(n*16 + h))*64 + d0;
        float4 a = ((const float4*)src)[0], b = ((const float4*)src)[1];
        unsigned w0 = cvtpk(a.x, a.y), w1 = cvtpk(a.z, a.w);
        unsigned w2 = cvtpk(b.x, b.y), w3 = cvtpk(b.z, b.w);
        *(uint4*)(relTb + (size_t)h*8192 + n*64 + d0) = make_uint4(w0, w1, w2, w3);
    }
}

// ---------------- shared GEMM body macros (128x128 tile, BK=64, dbuf, gload_lds) ----------
#define GEMM_STAGE(t, buf)                                                             \
    {                                                                                  \
        const int k0s = (t) * 64;                                                      \
        _Pragma("unroll")                                                              \
        for (int j = 0; j < 4; ++j) {                                                  \
            GLOAD16(agp + (size_t)(j*32 + srow)*1024 + k0s, &Als[buf][0] + j*2048 + tid*8); \
            GLOAD16(bgp + (size_t)(j*32 + srow)*1024 + k0s, &Bls[buf][0] + j*2048 + tid*8); \
        }                                                                              \
    }

#define GEMM_COMPUTE(buf)                                                              \
    {                                                                                  \
        _Pragma("unroll")                                                              \
        for (int ks = 0; ks < 2; ++ks) {                                               \
            bf16x8 af[4], bfr[4];                                                      \
            _Pragma("unroll")                                                          \
            for (int m = 0; m < 4; ++m)                                                \
                af[m] = *(const bf16x8*)&Als[buf][(wr + m*16 + (lane & 15))*64 + ks*32 + (lane >> 4)*8]; \
            _Pragma("unroll")                                                          \
            for (int n = 0; n < 4; ++n)                                                \
                bfr[n] = *(const bf16x8*)&Bls[buf][(wc + n*16 + (lane & 15))*64 + ks*32 + (lane >> 4)*8]; \
            _Pragma("unroll")                                                          \
            for (int m = 0; m < 4; ++m)                                                \
                _Pragma("unroll")                                                      \
                for (int n = 0; n < 4; ++n)                                            \
                    acc[m][n] = __builtin_amdgcn_mfma_f32_16x16x32_bf16(af[m], bfr[n], acc[m][n], 0, 0, 0); \
        }                                                                              \
    }

// ---------------- fused QKV GEMM: z=0 -> q fp32 [B,H,S,D]; z=1 -> k fp32; z=2 -> vT bf16 ----
__global__ __launch_bounds__(256) void gemm_qkv(const unsigned short* __restrict__ A,
    const unsigned short* __restrict__ wtq, const unsigned short* __restrict__ wtk,
    const unsigned short* __restrict__ wtv,
    float* __restrict__ qf, float* __restrict__ kf, unsigned short* __restrict__ vTb)
{
    __shared__ __align__(16) unsigned short Als[2][8192];
    __shared__ __align__(16) unsigned short Bls[2][8192];
    const int z = blockIdx.z;
    const unsigned short* Bt = (z == 0) ? wtq : (z == 1) ? wtk : wtv;

    const int tid  = threadIdx.x;
    const int wave = tid >> 6, lane = tid & 63;
    const int wr = (wave >> 1) * 64, wc = (wave & 1) * 64;
    const int bx = blockIdx.x, by = blockIdx.y;
    const int srow = tid >> 3;
    const unsigned short* agp = A  + (size_t)(by*128)*1024 + (tid & 7)*8;
    const unsigned short* bgp = Bt + (size_t)(bx*128)*1024 + (tid & 7)*8;

    f32x4 acc[4][4];
#pragma unroll
    for (int m = 0; m < 4; ++m)
#pragma unroll
        for (int n = 0; n < 4; ++n) acc[m][n] = (f32x4)0.f;

    GEMM_STAGE(0, 0);
    __syncthreads();
    int cur = 0;
    for (int t = 0; t < 16; ++t) {
        if (t < 15) GEMM_STAGE(t + 1, cur ^ 1);
        GEMM_COMPUTE(cur);
        __syncthreads();
        cur ^= 1;
    }

#pragma unroll
    for (int m = 0; m < 4; ++m) {
        const int r0 = by*128 + wr + m*16 + (lane >> 4)*4;
#pragma unroll
        for (int n = 0; n < 4; ++n) {
            const int col = bx*128 + wc + n*16 + (lane & 15);
            if (z == 2) {
                const int bb = r0 >> 11, ss = r0 & 2047;
                const int hh = col >> 6, dd = col & 63;
                unsigned r01 = cvtpk(acc[m][n][0], acc[m][n][1]);
                unsigned r23 = cvtpk(acc[m][n][2], acc[m][n][3]);
                *(uint2*)(vTb + (((size_t)bb*16 + hh)*64 + dd)*2048 + ss) = make_uint2(r01, r23);
            } else {
                float* C = z ? kf : qf;
#pragma unroll
                for (int rg = 0; rg < 4; ++rg) {
                    const int row = r0 + rg;
                    const int bb = row >> 11, ss = row & 2047;
                    const int hh = col >> 6,  dd = col & 63;
                    C[(((size_t)bb*16 + hh)*2048 + ss)*64 + dd] = acc[m][n][rg];
                }
            }
        }
    }
}

// ---------------- Wo GEMM: C fp32 row-major ----------------
__global__ __launch_bounds__(256) void gemm_o(const unsigned short* __restrict__ A,
                                              const unsigned short* __restrict__ Bt,
                                              float* __restrict__ C)
{
    __shared__ __align__(16) unsigned short Als[2][8192];
    __shared__ __align__(16) unsigned short Bls[2][8192];
    const int tid  = threadIdx.x;
    const int wave = tid >> 6, lane = tid & 63;
    const int wr = (wave >> 1) * 64, wc = (wave & 1) * 64;
    const int bx = blockIdx.x, by = blockIdx.y;
    const int srow = tid >> 3;
    const unsigned short* agp = A  + (size_t)(by*128)*1024 + (tid & 7)*8;
    const unsigned short* bgp = Bt + (size_t)(bx*128)*1024 + (tid & 7)*8;

    f32x4 acc[4][4];
#pragma unroll
    for (int m = 0; m < 4; ++m)
#pragma unroll
        for (int n = 0; n < 4; ++n) acc[m][n] = (f32x4)0.f;

    GEMM_STAGE(0, 0);
    __syncthreads();
    int cur = 0;
    for (int t = 0; t < 16; ++t) {
        if (t < 15) GEMM_STAGE(t + 1, cur ^ 1);
        GEMM_COMPUTE(cur);
        __syncthreads();
        cur ^= 1;
    }

#pragma unroll
    for (int m = 0; m < 4; ++m) {
        const int r0 = by*128 + wr + m*16 + (lane >> 4)*4;
#pragma unroll
        for (int n = 0; n < 4; ++n) {
            const int col = bx*128 + wc + n*16 + (lane & 15);
#pragma unroll
            for (int rg = 0; rg < 4; ++rg)
                C[(size_t)(r0 + rg)*1024 + col] = acc[m][n][rg];
        }
    }
}

// ---------------- RoPE: fp32 q/k [B,H,S,D] -> bf16 qb/kb ----------------
__global__ void rope_bf16(const float* __restrict__ qf, const float* __restrict__ kf,
                          unsigned short* __restrict__ qb, unsigned short* __restrict__ kb)
{
    const int t = blockIdx.x * 256 + threadIdx.x;
    const int ten = t >> 21;
    const int r = t & ((1 << 21) - 1);
    const int dd = r & 31;
    const int s  = (r >> 5) & 2047;
    const int bh = r >> 16;
    const float* p = ten ? kf : qf;
    unsigned short* o = ten ? kb : qb;
    const size_t base = ((size_t)bh*2048 + s)*64;
    const float x0 = p[base + dd];
    const float x1 = p[base + dd + 32];
    const float f0 = (float)(dd >> 1);
    const float CC = 0.41524101186092029f;           // log2(10000)/32
    const float if0 = exp2f(-f0 * CC);
    const float if1 = exp2f(-(f0 + 16.f) * CC);
    const float a0 = (float)s * if0;
    const float a1 = (float)s * if1;
    o[base + dd]      = f2bf(x0 * cosf(a0) - x1 * sinf(a0));
    o[base + dd + 32] = f2bf(x1 * cosf(a1) + x0 * sinf(a1));
}

// ---------------- qrel via MFMA (verified r10) ----------------
__global__ __launch_bounds__(256) void qrel_mfma(const unsigned short* __restrict__ qb,
                                                 const unsigned short* __restrict__ relTb,
                                                 unsigned short* __restrict__ qrelb)
{
    __shared__ __align__(16) unsigned short Rls[8192];   // 128 buckets x 64
    __shared__ __align__(16) unsigned short Qls[8192];   // 128 s-rows  x 64
    const int tid  = threadIdx.x;
    const int wave = tid >> 6, lane = tid & 63;
    const int wr = (wave >> 1) * 64;     // bucket offset
    const int wc = (wave & 1) * 64;      // s offset
    const int s0 = blockIdx.x * 128;
    const int bh = blockIdx.y;
    const int h  = bh & 15;

    const unsigned short* qsrc = qb + ((size_t)bh*2048 + s0)*64;
    const unsigned short* rsrc = relTb + (size_t)h*8192;
#pragma unroll
    for (int j = 0; j < 4; ++j) {
        GLOAD16(rsrc + j*2048 + tid*8, &Rls[0] + j*2048 + tid*8);
        GLOAD16(qsrc + j*2048 + tid*8, &Qls[0] + j*2048 + tid*8);
    }

    f32x4 acc[4][4];
#pragma unroll
    for (int m = 0; m < 4; ++m)
#pragma unroll
        for (int n = 0; n < 4; ++n) acc[m][n] = (f32x4)0.f;

    __syncthreads();

#pragma unroll
    for (int ks = 0; ks < 2; ++ks) {
        bf16x8 rf[4], qf[4];
#pragma unroll
        for (int m = 0; m < 4; ++m)
            rf[m] = *(const bf16x8*)&Rls[(wr + m*16 + (lane & 15))*64 + ks*32 + (lane >> 4)*8];
#pragma unroll
        for (int n = 0; n < 4; ++n)
            qf[n] = *(const bf16x8*)&Qls[(wc + n*16 + (lane & 15))*64 + ks*32 + (lane >> 4)*8];
#pragma unroll
        for (int m = 0; m < 4; ++m)
#pragma unroll
            for (int n = 0; n < 4; ++n)
                acc[m][n] = __builtin_amdgcn_mfma_f32_16x16x32_bf16(rf[m], qf[n], acc[m][n], 0, 0, 0);
    }

#pragma unroll
    for (int m = 0; m < 4; ++m) {
        const int bkt0 = wr + m*16 + (lane >> 4)*4;
#pragma unroll
        for (int n = 0; n < 4; ++n) {
            const int srow = s0 + wc + n*16 + (lane & 15);
            unsigned r01 = cvtpk(acc[m][n][0], acc[m][n][1]);
            unsigned r23 = cvtpk(acc[m][n][2], acc[m][n][3]);
            *(uint2*)(qrelb + ((size_t)bh*2048 + srow)*128 + bkt0) = make_uint2(r01, r23);
        }
    }
}

// ---------------- MFMA causal flash attention, 64-key tiles, paired 2-pass balance ----------
// 512 blocks; block (bh, px) runs q-tiles px and 31-px -> exactly 33 key-tiles per block,
// 66 per CU: perfect static balance. Bucket computed arithmetically (no LDS chain).
__global__ __launch_bounds__(256) void flash_mfma(
    const unsigned short* __restrict__ qb, const unsigned short* __restrict__ kb,
    const unsigned short* __restrict__ vT, const unsigned short* __restrict__ qrelb,
    unsigned short* __restrict__ ctxb)
{
    __shared__ __align__(16) unsigned short kls[4096];    // 64 keys x 64 d (swizzled granules)
    __shared__ __align__(16) unsigned short vtls[4096];   // 64 d x 64 keys (swizzled granules)
    __shared__ __align__(16) unsigned short qrels[64*136];

    const int tid = threadIdx.x;
    const int id  = blockIdx.x;                // 0..511
    const int bh  = id & 31;                   // head -> XCD locality
    const int px  = id >> 5;                   // 0..15 -> pair (px, 31-px)

    const int w   = tid >> 6;
    const int l   = tid & 63;
    const int q15 = l & 15;
    const int g   = l >> 4;

    // staging setup (pass-independent): waves 0,1 -> K, waves 2,3 -> V^T
    const size_t headoff = (size_t)bh * 2048 * 64;
    const unsigned short* gbase;
    int jstride;
    char* lbase;
    if (tid < 128) { gbase = kb + headoff; jstride = 64; lbase = (char*)kls; }
    else           { gbase = vT + headoff; jstride = 1;  lbase = (char*)vtls; }
    int soff[4]; char* ldst[4];
#pragma unroll
    for (int i = 0; i < 4; ++i) {
        const int D = (tid & 127)*16 + i*2048;
        const int r = D >> 7, c = (D >> 4) & 7;
        soff[i] = (tid < 128) ? (r*64 + ((c ^ (r & 7))*8))
                              : (r*2048 + ((c ^ (r & 7))*8));
        ldst[i] = lbase + D;
    }

    const float SCL = 0.1803368801111204f;      // (1/8)*log2(e)
    const int qrow_lds = (w*16 + q15) * 136;
    const int srcA = ((2*g) & 3)*16 + q15;
    const int srcB = ((2*g + 1) & 3)*16 + q15;

    for (int pp = 0; pp < 2; ++pp) {
        const int bxc = pp ? (31 - px) : px;
        const int i0  = bxc * 64;
        const int iq  = i0 + w*16 + q15;

        __syncthreads();                        // prev pass finished reading qrels
        for (int idx = tid; idx < 1024; idx += 256) {
            const int r = idx >> 4, c8 = idx & 15;
            uint4 vv = *(const uint4*)(qrelb + ((size_t)bh*2048 + i0 + r)*128 + c8*8);
            *(uint4*)&qrels[r*136 + c8*8] = vv;
        }

        bf16x8 qf0, qf1;
        {
            const unsigned short* qrow = qb + ((size_t)bh*2048 + i0 + w*16 + q15)*64;
            qf0 = *(const bf16x8*)(qrow + g*8);
            qf1 = *(const bf16x8*)(qrow + 32 + g*8);
        }

        f32x4 acc[4];
#pragma unroll
        for (int d = 0; d < 4; ++d) acc[d] = (f32x4)0.f;
        float mrun = -INFINITY, lsum = 0.f;

        const int ntiles = bxc + 1;
        for (int t = 0; t < ntiles; ++t) {
            const int j0 = t * 64;
            __syncthreads();                    // prev tile consumed (t=0: qrels staged)
            {
                const unsigned short* gt = gbase + (size_t)j0 * jstride;
#pragma unroll
                for (int i = 0; i < 4; ++i) GLOAD16(gt + soff[i], ldst[i]);
            }
            __syncthreads();                    // vmcnt drained -> tile visible

            // swapped QK^T: 4 key-subtiles of 16
            f32x4 s[4];
#pragma unroll
            for (int ss = 0; ss < 4; ++ss) s[ss] = (f32x4)0.f;
#pragma unroll
            for (int ks = 0; ks < 2; ++ks) {
                const bf16x8 qq = ks ? qf1 : qf0;
                const int gr = ((ks*4 + g) ^ (q15 & 7)) * 8;
#pragma unroll
                for (int ss = 0; ss < 4; ++ss) {
                    bf16x8 kf = *(const bf16x8*)&kls[(ss*16 + q15)*64 + gr];
                    s[ss] = __builtin_amdgcn_mfma_f32_16x16x32_bf16(kf, qq, s[ss], 0, 0, 0);
                }
            }
            // bias + mask; bucket computed arithmetically (identical formula to table)
            float sv[16];
            float tmax = -INFINITY;
#pragma unroll
            for (int ss = 0; ss < 4; ++ss) {
#pragma unroll
                for (int r = 0; r < 4; ++r) {
                    const int rel = iq - (j0 + ss*16 + g*4 + r);
                    const int bi = rel < 0 ? 0 : rel;
                    int bkt;
                    if (bi < 64) bkt = bi;
                    else {
                        bkt = 64 + (int)(__log2f((float)bi) * 8.0f - 48.0f);
                        bkt = bkt > 127 ? 127 : bkt;
                    }
                    const float bias = bf2f(qrels[qrow_lds + bkt]);
                    const float val = (s[ss][r] + bias) * SCL;
                    sv[ss*4 + r] = (rel >= 0) ? val : -1e30f;
                    tmax = fmaxf(tmax, sv[ss*4 + r]);
                }
            }
            tmax = fmaxf(tmax, __shfl_xor(tmax, 16));
            tmax = fmaxf(tmax, __shfl_xor(tmax, 32));

            // defer-max: skip rescale when all columns grew <= 8 (p bounded by 2^8)
            float newm = mrun;
            if (!__all(tmax - mrun <= 8.0f)) {
                newm = fmaxf(mrun, tmax);
                const float corr = fexp2(mrun - newm);
                lsum *= corr;
#pragma unroll
                for (int d = 0; d < 4; ++d) {
                    acc[d][0] *= corr; acc[d][1] *= corr; acc[d][2] *= corr; acc[d][3] *= corr;
                }
                mrun = newm;
            }

            float p[16], ps = 0.f;
#pragma unroll
            for (int j = 0; j < 16; ++j) { p[j] = fexp2(sv[j] - newm); ps += p[j]; }
            ps += __shfl_xor(ps, 16);
            ps += __shfl_xor(ps, 32);
            lsum += ps;

            // two 32-key chunks: build P^T B-frag via cvt_pk + shuffles, then PV
#pragma unroll
            for (int ck = 0; ck < 2; ++ck) {
                unsigned w00 = cvtpk(p[8*ck+0], p[8*ck+1]);
                unsigned w01 = cvtpk(p[8*ck+2], p[8*ck+3]);
                unsigned w10 = cvtpk(p[8*ck+4], p[8*ck+5]);
                unsigned w11 = cvtpk(p[8*ck+6], p[8*ck+7]);
                unsigned a0 = (unsigned)__shfl((int)w00, srcA);
                unsigned b0 = (unsigned)__shfl((int)w10, srcA);
                unsigned a1 = (unsigned)__shfl((int)w01, srcA);
                unsigned b1 = (unsigned)__shfl((int)w11, srcA);
                unsigned a2 = (unsigned)__shfl((int)w00, srcB);
                unsigned b2 = (unsigned)__shfl((int)w10, srcB);
                unsigned a3 = (unsigned)__shfl((int)w01, srcB);
                unsigned b3 = (unsigned)__shfl((int)w11, srcB);
                union { unsigned u[4]; bf16x8 v; } pu;
                pu.u[0] = (g < 2) ? a0 : b0;
                pu.u[1] = (g < 2) ? a1 : b1;
                pu.u[2] = (g < 2) ? a2 : b2;
                pu.u[3] = (g < 2) ? a3 : b3;
#pragma unroll
                for (int dblk = 0; dblk < 4; ++dblk) {
                    const int d2 = dblk*16 + q15;
                    bf16x8 vf = *(const bf16x8*)&vtls[d2*64 + (((ck*4 + g) ^ (d2 & 7))*8)];
                    acc[dblk] = __builtin_amdgcn_mfma_f32_16x16x32_bf16(vf, pu.v, acc[dblk], 0, 0, 0);
                }
            }
        }

        const float inv = 1.0f / lsum;
        const int s2 = i0 + w*16 + q15;
        const int b2 = bh >> 4, hh = bh & 15;
        unsigned short* obase = ctxb + (((size_t)b2*2048 + s2)*16 + hh)*64;
#pragma unroll
        for (int dblk = 0; dblk < 4; ++dblk) {
            const int d0 = dblk*16 + g*4;
            unsigned r01 = cvtpk(acc[dblk][0]*inv, acc[dblk][1]*inv);
            unsigned r23 = cvtpk(acc[dblk][2]*inv, acc[dblk][3]*inv);
            *(uint2*)(obase + d0) = make_uint2(r01, r23);
        }
    }
}

extern "C" void kernel_launch(void* const* d_in, const int* in_sizes, int n_in,
                              void* d_out, int out_size, void* d_ws, size_t ws_size,
                              hipStream_t stream)
{
    const float* x   = (const float*)d_in[0];
    const float* Wq  = (const float*)d_in[1];
    const float* Wk  = (const float*)d_in[2];
    const float* Wv  = (const float*)d_in[3];
    const float* Wo  = (const float*)d_in[4];
    const float* rel = (const float*)d_in[5];

    float* ws = (float*)d_ws;
    float* qf32 = ws;                                           // dead after rope
    float* kf32 = ws + 4194304;                                 // dead after rope
    unsigned short* qb    = (unsigned short*)(ws + 8388608);    // 4,194,304 bf16
    unsigned short* kbb   = (unsigned short*)(ws + 10485760);   // 4,194,304 bf16
    unsigned short* qrelb = (unsigned short*)(ws + 12582912);   // 8,388,608 bf16 (4M floats)
    unsigned short* vTb   = (unsigned short*)(ws + 16777216);   // 4,194,304 bf16
    unsigned short* xb    = (unsigned short*)(ws + 18874368);   // 4,194,304 bf16
    unsigned short* wtq   = (unsigned short*)(ws + 20971520);   // 1,048,576 bf16 each
    unsigned short* wtk   = (unsigned short*)(ws + 21495808);
    unsigned short* wtv   = (unsigned short*)(ws + 22020096);
    unsigned short* wto   = (unsigned short*)(ws + 22544384);
    unsigned short* relTb = (unsigned short*)(ws + 23068672);   // 131,072 bf16
    unsigned short* ctxb  = (unsigned short*)ws;                // over qf32 (dead by then)

    prep<<<3136, 256, 0, stream>>>(x, Wq, Wk, Wv, Wo, rel, xb, wtq, wtk, wtv, wto, relTb);
    gemm_qkv<<<dim3(8, 32, 3), 256, 0, stream>>>(xb, wtq, wtk, wtv, qf32, kf32, vTb);
    rope_bf16<<<16384, 256, 0, stream>>>(qf32, kf32, qb, kbb);
    qrel_mfma<<<dim3(16, 32), 256, 0, stream>>>(qb, relTb, qrelb);
    flash_mfma<<<512, 256, 0, stream>>>(qb, kbb, vTb, qrelb, ctxb);
    gemm_o<<<dim3(8, 32), 256, 0, stream>>>(ctxb, wto, (float*)d_out);
}

// Round 13
// 191.020 us; speedup vs baseline: 47.6358x; 1.0732x over previous
//
#include <hip/hip_runtime.h>
#include <hip/hip_bf16.h>
#include <math.h>

// Problem constants: B=2, S=2048, E=1024, H=16, D=64, buckets 0..127 (causal => rel>=0)

typedef __attribute__((ext_vector_type(8))) short bf16x8;
typedef __attribute__((ext_vector_type(4))) float f32x4;

static __device__ __forceinline__ unsigned short f2bf(float x) {
    unsigned u = __float_as_uint(x);
    unsigned r = (u + 0x7fffu + ((u >> 16) & 1u)) >> 16;   // RNE
    return (unsigned short)r;
}
static __device__ __forceinline__ float bf2f(unsigned short h) {
    return __uint_as_float(((unsigned)h) << 16);
}
static __device__ __forceinline__ unsigned cvtpk(float lo, float hi) {
    unsigned r;
    asm("v_cvt_pk_bf16_f32 %0, %1, %2" : "=v"(r) : "v"(lo), "v"(hi));
    return r;   // D[15:0]=bf16(lo), D[31:16]=bf16(hi)
}
static __device__ __forceinline__ float fexp2(float x) {
    return __builtin_amdgcn_exp2f(x);
}

// async 16B global->LDS (HW uses wave-uniform LDS base + lane*16 -> dest must be linear)
#define GLOAD16(gp, lp)                                                            \
    __builtin_amdgcn_global_load_lds(                                              \
        (const __attribute__((address_space(1))) unsigned int*)(gp),               \
        (__attribute__((address_space(3))) unsigned int*)(lp), 16, 0, 0)

// ---------------- fused prep: x->bf16 | 4x W transpose->bf16 | relT ----------------
__global__ void prep(const float* __restrict__ x,
                     const float* __restrict__ W0, const float* __restrict__ W1,
                     const float* __restrict__ W2, const float* __restrict__ W3,
                     const float* __restrict__ rel,
                     unsigned short* __restrict__ xb,
                     unsigned short* __restrict__ T0, unsigned short* __restrict__ T1,
                     unsigned short* __restrict__ T2, unsigned short* __restrict__ T3,
                     unsigned short* __restrict__ relTb)
{
    __shared__ unsigned short tls[64][65];
    const int id  = blockIdx.x;
    const int tid = threadIdx.x;
    if (id < 2048) {                         // tobf16: x -> xb
        const size_t t = (size_t)id * 256 + tid;
        const float4* p = (const float4*)(x + t*8);
        float4 a = p[0], b = p[1];
        unsigned w0 = cvtpk(a.x, a.y), w1 = cvtpk(a.z, a.w);
        unsigned w2 = cvtpk(b.x, b.y), w3 = cvtpk(b.z, b.w);
        *(uint4*)(xb + t*8) = make_uint4(w0, w1, w2, w3);
    } else if (id < 3072) {                  // transp4
        const int local = id - 2048;
        const int z  = local >> 8;
        const float* W = (z == 0) ? W0 : (z == 1) ? W1 : (z == 2) ? W2 : W3;
        unsigned short* Wt = (z == 0) ? T0 : (z == 1) ? T1 : (z == 2) ? T2 : T3;
        const int bb  = local & 255;
        const int bxt = bb & 15;
        const int byt = bb >> 4;
        const int r   = tid >> 2;
        const int c0  = (tid & 3) * 16;
        const float* src = W + (size_t)(byt*64 + r)*1024 + bxt*64 + c0;
#pragma unroll
        for (int j = 0; j < 4; ++j) {
            float4 vv = ((const float4*)src)[j];
            tls[c0 + j*4 + 0][r] = f2bf(vv.x);
            tls[c0 + j*4 + 1][r] = f2bf(vv.y);
            tls[c0 + j*4 + 2][r] = f2bf(vv.z);
            tls[c0 + j*4 + 3][r] = f2bf(vv.w);
        }
        __syncthreads();
        unsigned short* dst = Wt + (size_t)(bxt*64 + r)*1024 + byt*64 + c0;
        unsigned w[8];
#pragma unroll
        for (int j = 0; j < 8; ++j)
            w[j] = (unsigned)tls[r][c0 + 2*j] | ((unsigned)tls[r][c0 + 2*j + 1] << 16);
        *(uint4*)(dst)     = make_uint4(w[0], w[1], w[2], w[3]);
        *(uint4*)(dst + 8) = make_uint4(w[4], w[5], w[6], w[7]);
    } else {                                 // relT: rel_emb -> [16][128][64] bf16
        const int t  = (id - 3072) * 256 + tid;
        const int d0 = (t & 7) * 8;
        const int n  = (t >> 3) & 127;
        const int h  = t >> 10;
        const float* src = rel + ((size_t)(n*16 + h))*64 + d0;
        float4 a = ((const float4*)src)[0], b = ((const float4*)src)[1];
        unsigned w0 = cvtpk(a.x, a.y), w1 = cvtpk(a.z, a.w);
        unsigned w2 = cvtpk(b.x, b.y), w3 = cvtpk(b.z, b.w);
        *(uint4*)(relTb + (size_t)h*8192 + n*64 + d0) = make_uint4(w0, w1, w2, w3);
    }
}

// ---------------- shared GEMM body macros (128x128 tile, BK=64, dbuf, gload_lds) ----------
#define GEMM_STAGE(t, buf)                                                             \
    {                                                                                  \
        const int k0s = (t) * 64;                                                      \
        _Pragma("unroll")                                                              \
        for (int j = 0; j < 4; ++j) {                                                  \
            GLOAD16(agp + (size_t)(j*32 + srow)*1024 + k0s, &Als[buf][0] + j*2048 + tid*8); \
            GLOAD16(bgp + (size_t)(j*32 + srow)*1024 + k0s, &Bls[buf][0] + j*2048 + tid*8); \
        }                                                                              \
    }

#define GEMM_COMPUTE(buf)                                                              \
    {                                                                                  \
        _Pragma("unroll")                                                              \
        for (int ks = 0; ks < 2; ++ks) {                                               \
            bf16x8 af[4], bfr[4];                                                      \
            _Pragma("unroll")                                                          \
            for (int m = 0; m < 4; ++m)                                                \
                af[m] = *(const bf16x8*)&Als[buf][(wr + m*16 + (lane & 15))*64 + ks*32 + (lane >> 4)*8]; \
            _Pragma("unroll")                                                          \
            for (int n = 0; n < 4; ++n)                                                \
                bfr[n] = *(const bf16x8*)&Bls[buf][(wc + n*16 + (lane & 15))*64 + ks*32 + (lane >> 4)*8]; \
            _Pragma("unroll")                                                          \
            for (int m = 0; m < 4; ++m)                                                \
                _Pragma("unroll")                                                      \
                for (int n = 0; n < 4; ++n)                                            \
                    acc[m][n] = __builtin_amdgcn_mfma_f32_16x16x32_bf16(af[m], bfr[n], acc[m][n], 0, 0, 0); \
        }                                                                              \
    }

// ---------------- fused QKV GEMM + RoPE: z=0 -> qb bf16; z=1 -> kb bf16; z=2 -> vT bf16 ----
// RoPE fused in-register: pair (dd, dd+32) = acc[m][n], acc[m][n+2] for n in {0,1}
// (dd = n*16 + (lane&15) < 32, same lane, same head).
__global__ __launch_bounds__(256) void gemm_qkv(const unsigned short* __restrict__ A,
    const unsigned short* __restrict__ wtq, const unsigned short* __restrict__ wtk,
    const unsigned short* __restrict__ wtv,
    unsigned short* __restrict__ qb, unsigned short* __restrict__ kbb,
    unsigned short* __restrict__ vTb)
{
    __shared__ __align__(16) unsigned short Als[2][8192];
    __shared__ __align__(16) unsigned short Bls[2][8192];
    const int z = blockIdx.z;
    const unsigned short* Bt = (z == 0) ? wtq : (z == 1) ? wtk : wtv;

    const int tid  = threadIdx.x;
    const int wave = tid >> 6, lane = tid & 63;
    const int wr = (wave >> 1) * 64, wc = (wave & 1) * 64;
    const int bx = blockIdx.x, by = blockIdx.y;
    const int srow = tid >> 3;
    const unsigned short* agp = A  + (size_t)(by*128)*1024 + (tid & 7)*8;
    const unsigned short* bgp = Bt + (size_t)(bx*128)*1024 + (tid & 7)*8;

    f32x4 acc[4][4];
#pragma unroll
    for (int m = 0; m < 4; ++m)
#pragma unroll
        for (int n = 0; n < 4; ++n) acc[m][n] = (f32x4)0.f;

    GEMM_STAGE(0, 0);
    __syncthreads();
    int cur = 0;
    for (int t = 0; t < 16; ++t) {
        if (t < 15) GEMM_STAGE(t + 1, cur ^ 1);
        GEMM_COMPUTE(cur);
        __syncthreads();
        cur ^= 1;
    }

    if (z == 2) {
#pragma unroll
        for (int m = 0; m < 4; ++m) {
            const int r0 = by*128 + wr + m*16 + (lane >> 4)*4;
#pragma unroll
            for (int n = 0; n < 4; ++n) {
                const int col = bx*128 + wc + n*16 + (lane & 15);
                const int bb = r0 >> 11, ss = r0 & 2047;
                const int hh = col >> 6, dd = col & 63;
                unsigned r01 = cvtpk(acc[m][n][0], acc[m][n][1]);
                unsigned r23 = cvtpk(acc[m][n][2], acc[m][n][3]);
                *(uint2*)(vTb + (((size_t)bb*16 + hh)*64 + dd)*2048 + ss) = make_uint2(r01, r23);
            }
        }
    } else {
        unsigned short* O = z ? kbb : qb;
        const float CC = 0.41524101186092029f;   // log2(10000)/32
#pragma unroll
        for (int n = 0; n < 2; ++n) {
            const int dd = n*16 + (lane & 15);   // < 32
            const float if0 = exp2f(-(float)(dd >> 1) * CC);
            const float if1 = exp2f(-(float)(16 + (dd >> 1)) * CC);
            const int col = bx*128 + wc + n*16 + (lane & 15);
            const int hh = col >> 6;
#pragma unroll
            for (int m = 0; m < 4; ++m) {
                const int r0 = by*128 + wr + m*16 + (lane >> 4)*4;
#pragma unroll
                for (int rg = 0; rg < 4; ++rg) {
                    const int row = r0 + rg;
                    const int bb = row >> 11, s = row & 2047;
                    const float x0 = acc[m][n][rg];
                    const float x1 = acc[m][n + 2][rg];
                    const float a0 = (float)s * if0;
                    const float a1 = (float)s * if1;
                    const float o0 = x0 * __cosf(a0) - x1 * __sinf(a0);
                    const float o1 = x1 * __cosf(a1) + x0 * __sinf(a1);
                    unsigned short* ob = O + (((size_t)bb*16 + hh)*2048 + s)*64 + dd;
                    ob[0]  = f2bf(o0);
                    ob[32] = f2bf(o1);
                }
            }
        }
    }
}

// ---------------- Wo GEMM: C fp32 row-major ----------------
__global__ __launch_bounds__(256) void gemm_o(const unsigned short* __restrict__ A,
                                              const unsigned short* __restrict__ Bt,
                                              float* __restrict__ C)
{
    __shared__ __align__(16) unsigned short Als[2][8192];
    __shared__ __align__(16) unsigned short Bls[2][8192];
    const int tid  = threadIdx.x;
    const int wave = tid >> 6, lane = tid & 63;
    const int wr = (wave >> 1) * 64, wc = (wave & 1) * 64;
    const int bx = blockIdx.x, by = blockIdx.y;
    const int srow = tid >> 3;
    const unsigned short* agp = A  + (size_t)(by*128)*1024 + (tid & 7)*8;
    const unsigned short* bgp = Bt + (size_t)(bx*128)*1024 + (tid & 7)*8;

    f32x4 acc[4][4];
#pragma unroll
    for (int m = 0; m < 4; ++m)
#pragma unroll
        for (int n = 0; n < 4; ++n) acc[m][n] = (f32x4)0.f;

    GEMM_STAGE(0, 0);
    __syncthreads();
    int cur = 0;
    for (int t = 0; t < 16; ++t) {
        if (t < 15) GEMM_STAGE(t + 1, cur ^ 1);
        GEMM_COMPUTE(cur);
        __syncthreads();
        cur ^= 1;
    }

#pragma unroll
    for (int m = 0; m < 4; ++m) {
        const int r0 = by*128 + wr + m*16 + (lane >> 4)*4;
#pragma unroll
        for (int n = 0; n < 4; ++n) {
            const int col = bx*128 + wc + n*16 + (lane & 15);
#pragma unroll
            for (int rg = 0; rg < 4; ++rg)
                C[(size_t)(r0 + rg)*1024 + col] = acc[m][n][rg];
        }
    }
}

// ---------------- qrel via MFMA (verified r10) ----------------
__global__ __launch_bounds__(256) void qrel_mfma(const unsigned short* __restrict__ qb,
                                                 const unsigned short* __restrict__ relTb,
                                                 unsigned short* __restrict__ qrelb)
{
    __shared__ __align__(16) unsigned short Rls[8192];   // 128 buckets x 64
    __shared__ __align__(16) unsigned short Qls[8192];   // 128 s-rows  x 64
    const int tid  = threadIdx.x;
    const int wave = tid >> 6, lane = tid & 63;
    const int wr = (wave >> 1) * 64;     // bucket offset
    const int wc = (wave & 1) * 64;      // s offset
    const int s0 = blockIdx.x * 128;
    const int bh = blockIdx.y;
    const int h  = bh & 15;

    const unsigned short* qsrc = qb + ((size_t)bh*2048 + s0)*64;
    const unsigned short* rsrc = relTb + (size_t)h*8192;
#pragma unroll
    for (int j = 0; j < 4; ++j) {
        GLOAD16(rsrc + j*2048 + tid*8, &Rls[0] + j*2048 + tid*8);
        GLOAD16(qsrc + j*2048 + tid*8, &Qls[0] + j*2048 + tid*8);
    }

    f32x4 acc[4][4];
#pragma unroll
    for (int m = 0; m < 4; ++m)
#pragma unroll
        for (int n = 0; n < 4; ++n) acc[m][n] = (f32x4)0.f;

    __syncthreads();

#pragma unroll
    for (int ks = 0; ks < 2; ++ks) {
        bf16x8 rf[4], qf[4];
#pragma unroll
        for (int m = 0; m < 4; ++m)
            rf[m] = *(const bf16x8*)&Rls[(wr + m*16 + (lane & 15))*64 + ks*32 + (lane >> 4)*8];
#pragma unroll
        for (int n = 0; n < 4; ++n)
            qf[n] = *(const bf16x8*)&Qls[(wc + n*16 + (lane & 15))*64 + ks*32 + (lane >> 4)*8];
#pragma unroll
        for (int m = 0; m < 4; ++m)
#pragma unroll
            for (int n = 0; n < 4; ++n)
                acc[m][n] = __builtin_amdgcn_mfma_f32_16x16x32_bf16(rf[m], qf[n], acc[m][n], 0, 0, 0);
    }

#pragma unroll
    for (int m = 0; m < 4; ++m) {
        const int bkt0 = wr + m*16 + (lane >> 4)*4;
#pragma unroll
        for (int n = 0; n < 4; ++n) {
            const int srow = s0 + wc + n*16 + (lane & 15);
            unsigned r01 = cvtpk(acc[m][n][0], acc[m][n][1]);
            unsigned r23 = cvtpk(acc[m][n][2], acc[m][n][3]);
            *(uint2*)(qrelb + ((size_t)bh*2048 + srow)*128 + bkt0) = make_uint2(r01, r23);
        }
    }
}

// ---------------- MFMA causal flash attention, 64-key tiles, dbuf staging ----------------
// 512 blocks; block (bh, px) runs q-tiles px and 31-px. Double-buffered K/V^T: GLOAD(t+1)
// issued before compute(t), ONE barrier per tile -> HBM latency hidden under compute.
__global__ __launch_bounds__(256) void flash_mfma(
    const unsigned short* __restrict__ qb, const unsigned short* __restrict__ kb,
    const unsigned short* __restrict__ vT, const unsigned short* __restrict__ qrelb,
    unsigned short* __restrict__ ctxb)
{
    __shared__ __align__(16) unsigned short kls[2][4096];   // [buf][64 keys x 64 d] swizzled
    __shared__ __align__(16) unsigned short vtls[2][4096];  // [buf][64 d x 64 keys] swizzled
    __shared__ __align__(16) unsigned short qrels[64*136];

    const int tid = threadIdx.x;
    const int id  = blockIdx.x;                // 0..511
    const int bh  = id & 31;                   // head -> XCD locality
    const int px  = id >> 5;                   // 0..15 -> pair (px, 31-px)

    const int w   = tid >> 6;
    const int l   = tid & 63;
    const int q15 = l & 15;
    const int g   = l >> 4;

    // staging setup: waves 0,1 -> K, waves 2,3 -> V^T; 4 GLOAD16/thread/tile
    const size_t headoff = (size_t)bh * 2048 * 64;
    const unsigned short* gbase;
    int jstride;
    if (tid < 128) { gbase = kb + headoff; jstride = 64; }
    else           { gbase = vT + headoff; jstride = 1;  }
    int soff[4], doff[4];
#pragma unroll
    for (int i = 0; i < 4; ++i) {
        const int D = (tid & 127)*16 + i*2048;
        const int r = D >> 7, c = (D >> 4) & 7;
        soff[i] = (tid < 128) ? (r*64 + ((c ^ (r & 7))*8))
                              : (r*2048 + ((c ^ (r & 7))*8));
        doff[i] = D;
    }

    const float SCL = 0.1803368801111204f;      // (1/8)*log2(e)
    const int qrow_lds = (w*16 + q15) * 136;
    const int srcA = ((2*g) & 3)*16 + q15;
    const int srcB = ((2*g + 1) & 3)*16 + q15;

    int cur = 0;
    for (int pp = 0; pp < 2; ++pp) {
        const int bxc = pp ? (31 - px) : px;
        const int i0  = bxc * 64;
        const int iq  = i0 + w*16 + q15;

        __syncthreads();                        // prev pass fully done (qrels + both bufs free)
        for (int idx = tid; idx < 1024; idx += 256) {
            const int r = idx >> 4, c8 = idx & 15;
            uint4 vv = *(const uint4*)(qrelb + ((size_t)bh*2048 + i0 + r)*128 + c8*8);
            *(uint4*)&qrels[r*136 + c8*8] = vv;
        }
        {   // prefetch tile 0 into buf cur
            char* lb = (tid < 128) ? (char*)kls[cur] : (char*)vtls[cur];
#pragma unroll
            for (int i = 0; i < 4; ++i) GLOAD16(gbase + soff[i], lb + doff[i]);
        }

        bf16x8 qf0, qf1;
        {
            const unsigned short* qrow = qb + ((size_t)bh*2048 + i0 + w*16 + q15)*64;
            qf0 = *(const bf16x8*)(qrow + g*8);
            qf1 = *(const bf16x8*)(qrow + 32 + g*8);
        }

        f32x4 acc[4];
#pragma unroll
        for (int d = 0; d < 4; ++d) acc[d] = (f32x4)0.f;
        float mrun = -INFINITY, lsum = 0.f;

        __syncthreads();                        // qrels staged + tile0 drained

        const int ntiles = bxc + 1;
        for (int t = 0; t < ntiles; ++t) {
            const int j0 = t * 64;
            if (t + 1 < ntiles) {               // prefetch t+1 into other buf (flies under compute)
                const unsigned short* gt = gbase + (size_t)(j0 + 64) * jstride;
                char* lb = (tid < 128) ? (char*)kls[cur ^ 1] : (char*)vtls[cur ^ 1];
#pragma unroll
                for (int i = 0; i < 4; ++i) GLOAD16(gt + soff[i], lb + doff[i]);
            }

            // swapped QK^T: 4 key-subtiles of 16
            f32x4 s[4];
#pragma unroll
            for (int ss = 0; ss < 4; ++ss) s[ss] = (f32x4)0.f;
#pragma unroll
            for (int ks = 0; ks < 2; ++ks) {
                const bf16x8 qq = ks ? qf1 : qf0;
                const int gr = ((ks*4 + g) ^ (q15 & 7)) * 8;
#pragma unroll
                for (int ss = 0; ss < 4; ++ss) {
                    bf16x8 kf = *(const bf16x8*)&kls[cur][(ss*16 + q15)*64 + gr];
                    s[ss] = __builtin_amdgcn_mfma_f32_16x16x32_bf16(kf, qq, s[ss], 0, 0, 0);
                }
            }
            // bias + mask; bucket computed arithmetically
            float sv[16];
            float tmax = -INFINITY;
#pragma unroll
            for (int ss = 0; ss < 4; ++ss) {
#pragma unroll
                for (int r = 0; r < 4; ++r) {
                    const int rel = iq - (j0 + ss*16 + g*4 + r);
                    const int bi = rel < 0 ? 0 : rel;
                    int bkt;
                    if (bi < 64) bkt = bi;
                    else {
                        bkt = 64 + (int)(__log2f((float)bi) * 8.0f - 48.0f);
                        bkt = bkt > 127 ? 127 : bkt;
                    }
                    const float bias = bf2f(qrels[qrow_lds + bkt]);
                    const float val = (s[ss][r] + bias) * SCL;
                    sv[ss*4 + r] = (rel >= 0) ? val : -1e30f;
                    tmax = fmaxf(tmax, sv[ss*4 + r]);
                }
            }
            tmax = fmaxf(tmax, __shfl_xor(tmax, 16));
            tmax = fmaxf(tmax, __shfl_xor(tmax, 32));

            // defer-max: skip rescale when all columns grew <= 8
            float newm = mrun;
            if (!__all(tmax - mrun <= 8.0f)) {
                newm = fmaxf(mrun, tmax);
                const float corr = fexp2(mrun - newm);
                lsum *= corr;
#pragma unroll
                for (int d = 0; d < 4; ++d) {
                    acc[d][0] *= corr; acc[d][1] *= corr; acc[d][2] *= corr; acc[d][3] *= corr;
                }
                mrun = newm;
            }

            float p[16], ps = 0.f;
#pragma unroll
            for (int j = 0; j < 16; ++j) { p[j] = fexp2(sv[j] - newm); ps += p[j]; }
            ps += __shfl_xor(ps, 16);
            ps += __shfl_xor(ps, 32);
            lsum += ps;

            // two 32-key chunks: build P^T B-frag via cvt_pk + shuffles, then PV
#pragma unroll
            for (int ck = 0; ck < 2; ++ck) {
                unsigned w00 = cvtpk(p[8*ck+0], p[8*ck+1]);
                unsigned w01 = cvtpk(p[8*ck+2], p[8*ck+3]);
                unsigned w10 = cvtpk(p[8*ck+4], p[8*ck+5]);
                unsigned w11 = cvtpk(p[8*ck+6], p[8*ck+7]);
                unsigned a0 = (unsigned)__shfl((int)w00, srcA);
                unsigned b0 = (unsigned)__shfl((int)w10, srcA);
                unsigned a1 = (unsigned)__shfl((int)w01, srcA);
                unsigned b1 = (unsigned)__shfl((int)w11, srcA);
                unsigned a2 = (unsigned)__shfl((int)w00, srcB);
                unsigned b2 = (unsigned)__shfl((int)w10, srcB);
                unsigned a3 = (unsigned)__shfl((int)w01, srcB);
                unsigned b3 = (unsigned)__shfl((int)w11, srcB);
                union { unsigned u[4]; bf16x8 v; } pu;
                pu.u[0] = (g < 2) ? a0 : b0;
                pu.u[1] = (g < 2) ? a1 : b1;
                pu.u[2] = (g < 2) ? a2 : b2;
                pu.u[3] = (g < 2) ? a3 : b3;
#pragma unroll
                for (int dblk = 0; dblk < 4; ++dblk) {
                    const int d2 = dblk*16 + q15;
                    bf16x8 vf = *(const bf16x8*)&vtls[cur][d2*64 + (((ck*4 + g) ^ (d2 & 7))*8)];
                    acc[dblk] = __builtin_amdgcn_mfma_f32_16x16x32_bf16(vf, pu.v, acc[dblk], 0, 0, 0);
                }
            }

            __syncthreads();                    // drains t+1 loads; all waves done with buf cur
            cur ^= 1;
        }

        const float inv = 1.0f / lsum;
        const int s2 = i0 + w*16 + q15;
        const int b2 = bh >> 4, hh = bh & 15;
        unsigned short* obase = ctxb + (((size_t)b2*2048 + s2)*16 + hh)*64;
#pragma unroll
        for (int dblk = 0; dblk < 4; ++dblk) {
            const int d0 = dblk*16 + g*4;
            unsigned r01 = cvtpk(acc[dblk][0]*inv, acc[dblk][1]*inv);
            unsigned r23 = cvtpk(acc[dblk][2]*inv, acc[dblk][3]*inv);
            *(uint2*)(obase + d0) = make_uint2(r01, r23);
        }
    }
}

extern "C" void kernel_launch(void* const* d_in, const int* in_sizes, int n_in,
                              void* d_out, int out_size, void* d_ws, size_t ws_size,
                              hipStream_t stream)
{
    const float* x   = (const float*)d_in[0];
    const float* Wq  = (const float*)d_in[1];
    const float* Wk  = (const float*)d_in[2];
    const float* Wv  = (const float*)d_in[3];
    const float* Wo  = (const float*)d_in[4];
    const float* rel = (const float*)d_in[5];

    float* ws = (float*)d_ws;
    unsigned short* qb    = (unsigned short*)(ws + 8388608);    // 4,194,304 bf16
    unsigned short* kbb   = (unsigned short*)(ws + 10485760);   // 4,194,304 bf16
    unsigned short* qrelb = (unsigned short*)(ws + 12582912);   // 8,388,608 bf16 (4M floats)
    unsigned short* vTb   = (unsigned short*)(ws + 16777216);   // 4,194,304 bf16
    unsigned short* xb    = (unsigned short*)(ws + 18874368);   // 4,194,304 bf16
    unsigned short* wtq   = (unsigned short*)(ws + 20971520);   // 1,048,576 bf16 each
    unsigned short* wtk   = (unsigned short*)(ws + 21495808);
    unsigned short* wtv   = (unsigned short*)(ws + 22020096);
    unsigned short* wto   = (unsigned short*)(ws + 22544384);
    unsigned short* relTb = (unsigned short*)(ws + 23068672);   // 131,072 bf16
    unsigned short* ctxb  = (unsigned short*)ws;                // first region (free)

    prep<<<3136, 256, 0, stream>>>(x, Wq, Wk, Wv, Wo, rel, xb, wtq, wtk, wtv, wto, relTb);
    gemm_qkv<<<dim3(8, 32, 3), 256, 0, stream>>>(xb, wtq, wtk, wtv, qb, kbb, vTb);
    qrel_mfma<<<dim3(16, 32), 256, 0, stream>>>(qb, relTb, qrelb);
    flash_mfma<<<512, 256, 0, stream>>>(qb, kbb, vTb, qrelb, ctxb);
    gemm_o<<<dim3(8, 32), 256, 0, stream>>>(ctxb, wto, (float*)d_out);
}